// Round 3
// baseline (5366.525 us; speedup 1.0000x reference)
//
#include <hip/hip_runtime.h>
#include <math.h>

typedef unsigned int u32;
typedef unsigned short u16;
typedef short s8v __attribute__((ext_vector_type(8)));
typedef float f4v __attribute__((ext_vector_type(4)));
typedef u32 u4v __attribute__((ext_vector_type(4)));

#define B_ 4
#define C_ 64
#define HW 4096
#define L_ 4096
#define D_ 576
#define MW 256
#define SCALE 10.0f
#define EPS 1e-4f
#define TAU 0.015f

__device__ __forceinline__ u32 bf16rn(float x) {
  u32 u = __float_as_uint(x);
  return (u + 0x7fffu + ((u >> 16) & 1u)) >> 16;
}
__device__ __forceinline__ float bf16f(u32 h) { return __uint_as_float(h << 16); }

__device__ __forceinline__ void gld16(const void* g, void* l) {
  __builtin_amdgcn_global_load_lds((const __attribute__((address_space(1))) void*)g,
                                   (__attribute__((address_space(3))) void*)l, 16, 0, 0);
}

// ---------- small prep kernels ----------
__global__ __launch_bounds__(256) void k_mp(const float* __restrict__ mask, float* __restrict__ mp) {
  int idx = blockIdx.x * 256 + threadIdx.x;
  int b = idx >> 12, p = idx & 4095;
  int y = p >> 6, x = p & 63;
  const float* mb = mask + (size_t)b * MW * MW;
  float s = 0.f;
  #pragma unroll
  for (int i = 0; i < 4; ++i)
    #pragma unroll
    for (int j = 0; j < 4; ++j)
      s += mb[(y * 4 + i) * MW + x * 4 + j];
  mp[idx] = s * (1.f / 16.f);
}

__global__ __launch_bounds__(256) void k_m0(const float* __restrict__ mp, float* __restrict__ m0) {
  int idx = blockIdx.x * 256 + threadIdx.x;   // l*9 + t
  int l = idx / 9, t = idx - l * 9;
  int ly = l >> 6, lx = l & 63;
  int i = t / 3, j = t - i * 3;
  int yy = ly + i - 1, xx = lx + j - 1;
  float v = 0.f;
  if ((unsigned)yy < 64u && (unsigned)xx < 64u) v = mp[(yy << 6) + xx];
  m0[idx] = v;
}

__global__ __launch_bounds__(256) void k_fm(const float* __restrict__ f, const float* __restrict__ mp,
                                            float* __restrict__ fm) {
  int idx = blockIdx.x * 256 + threadIdx.x;
  int p = idx & 4095;
  int b = idx >> 18;
  fm[idx] = f[idx] * (1.f - mp[(b << 12) + p]);
}

// patches row-major [l][576] -> hi/lo bf16 planes
__global__ __launch_bounds__(256) void k_patch(const float* __restrict__ img,
                                               const float* __restrict__ m0,
                                               u16* __restrict__ oh, u16* __restrict__ ol) {
  int idx = blockIdx.x * 256 + threadIdx.x;   // l*576 + d
  int l = idx / D_;
  int d = idx - l * D_;
  int c = d / 9, t = d - c * 9;
  int ly = l >> 6, lx = l & 63;
  int i = t / 3, j = t - i * 3;
  int yy = ly + i - 1, xx = lx + j - 1;
  float v = 0.f;
  if ((unsigned)yy < 64u && (unsigned)xx < 64u) v = img[(c << 12) + (yy << 6) + xx];
  if (m0) v *= m0[l * 9 + t];
  u32 h = bf16rn(v);
  oh[idx] = (u16)h;
  ol[idx] = (u16)bf16rn(v - bf16f(h));
}

// transposed patches [d<640][4096 l] -> hi/lo bf16 (rows 576..639 zeroed)
__global__ __launch_bounds__(256) void k_patchT(const float* __restrict__ img,
                                                const float* __restrict__ m0,
                                                u16* __restrict__ oh, u16* __restrict__ ol) {
  int idx = blockIdx.x * 256 + threadIdx.x;   // d*4096 + l
  int d = idx >> 12, l = idx & 4095;
  float v = 0.f;
  if (d < D_) {
    int c = d / 9, t = d - c * 9;
    int ly = l >> 6, lx = l & 63;
    int i = t / 3, j = t - i * 3;
    int yy = ly + i - 1, xx = lx + j - 1;
    if ((unsigned)yy < 64u && (unsigned)xx < 64u)
      v = img[(c << 12) + (yy << 6) + xx] * m0[l * 9 + t];
  }
  u32 h = bf16rn(v);
  oh[idx] = (u16)h;
  ol[idx] = (u16)bf16rn(v - bf16f(h));
}

__global__ __launch_bounds__(256) void k_norm(const u16* __restrict__ wh, const u16* __restrict__ wl,
                                              float* __restrict__ normv) {
  int l = blockIdx.x * 4 + (threadIdx.x >> 6);
  int lane = threadIdx.x & 63;
  const u16* rh = wh + (size_t)l * D_;
  const u16* rl = wl + (size_t)l * D_;
  float s = 0.f;
  for (int i = lane; i < D_; i += 64) {
    float v = bf16f(rh[i]) + bf16f(rl[i]);
    s += v * v;
  }
  #pragma unroll
  for (int off = 32; off; off >>= 1) s += __shfl_down(s, off);
  if (lane == 0) normv[l] = sqrtf(s + EPS);
}

// ---------- MFMA split-bf16 GEMM ----------
template<bool PACKED_A, bool DIVN>
__global__ __launch_bounds__(256) void k_mfma(
    const void* __restrict__ Ah_, const u16* __restrict__ Al,
    const u16* __restrict__ Bh, const u16* __restrict__ Bl,
    const float* __restrict__ normv, void* __restrict__ Cout,
    int lda, int ldb, int ldc, int Nlim, int kPerZ, int nChunks, int czStride)
{
  __shared__ u32 lds[8192];
  u16* ldsu = (u16*)lds;
  const int tid = threadIdx.x;
  const int lane = tid & 63, wid = tid >> 6;
  const int wr = wid >> 1, wc = wid & 1;
  const int kq = lane >> 4, li = lane & 15;

  int nwg = gridDim.x * gridDim.y;
  int bid = blockIdx.y * gridDim.x + blockIdx.x;
  int cpx = nwg >> 3;
  int swz = (bid & 7) * cpx + (bid >> 3);
  int bx = swz % gridDim.x, by = swz / gridDim.x;
  const int m0 = by * 128, n0 = bx * 128;
  const int kz = blockIdx.z * kPerZ;

  f4v acc[4][4] = {};

  for (int kc = 0; kc < nChunks; ++kc) {
    int k0 = kz + kc * 32;
    if (PACKED_A) {
      const u32* Ap = (const u32*)Ah_;
      #pragma unroll
      for (int i = 0; i < 4; ++i) {
        int s = tid + i * 256;
        int r = s >> 3, ks = s & 7;
        int kg = ks ^ (r & 7);
        gld16(Ap + (u32)(m0 + r) * (u32)lda + (u32)(k0 + kg * 4), (char*)lds + s * 16);
      }
    } else {
      const u16* Ahp = (const u16*)Ah_;
      #pragma unroll
      for (int i = 0; i < 2; ++i) {
        int s = tid + i * 256;
        int r = s >> 2, ks = s & 3;
        int kg = ks ^ ((r >> 1) & 3);
        u32 go = (u32)(m0 + r) * (u32)lda + (u32)(k0 + kg * 8);
        gld16(Ahp + go, (char*)lds + s * 16);
        gld16(Al + go, (char*)lds + 8192 + s * 16);
      }
    }
    #pragma unroll
    for (int i = 0; i < 2; ++i) {
      int s = tid + i * 256;
      int r = s >> 2, ks = s & 3;
      int kg = ks ^ ((r >> 1) & 3);
      u32 go = (u32)(n0 + r) * (u32)ldb + (u32)(k0 + kg * 8);
      gld16(Bh + go, (char*)lds + 16384 + s * 16);
      gld16(Bl + go, (char*)lds + 24576 + s * 16);
    }
    __syncthreads();

    s8v ah[4], alv[4];
    if (PACKED_A) {
      #pragma unroll
      for (int mf = 0; mf < 4; ++mf) {
        int r = wr * 64 + mf * 16 + li;
        int rb = r * 32, sw = r & 7;
        u4v p0 = *(const u4v*)&lds[rb + (((kq * 2 + 0) ^ sw) << 2)];
        u4v p1 = *(const u4v*)&lds[rb + (((kq * 2 + 1) ^ sw) << 2)];
        s8v h = { (short)(p0[0] >> 16), (short)(p0[1] >> 16), (short)(p0[2] >> 16), (short)(p0[3] >> 16),
                  (short)(p1[0] >> 16), (short)(p1[1] >> 16), (short)(p1[2] >> 16), (short)(p1[3] >> 16) };
        s8v lo = { (short)p0[0], (short)p0[1], (short)p0[2], (short)p0[3],
                   (short)p1[0], (short)p1[1], (short)p1[2], (short)p1[3] };
        ah[mf] = h; alv[mf] = lo;
      }
    } else {
      #pragma unroll
      for (int mf = 0; mf < 4; ++mf) {
        int r = wr * 64 + mf * 16 + li;
        int off = r * 32 + (kq ^ ((r >> 1) & 3)) * 8;
        ah[mf]  = *(const s8v*)&ldsu[off];
        alv[mf] = *(const s8v*)&ldsu[4096 + off];
      }
    }
    #pragma unroll
    for (int nf = 0; nf < 4; ++nf) {
      int r = wc * 64 + nf * 16 + li;
      int off = r * 32 + (kq ^ ((r >> 1) & 3)) * 8;
      s8v bh = *(const s8v*)&ldsu[8192 + off];
      s8v bl = *(const s8v*)&ldsu[12288 + off];
      #pragma unroll
      for (int mf = 0; mf < 4; ++mf) {
        acc[mf][nf] = __builtin_amdgcn_mfma_f32_16x16x32_bf16(ah[mf],  bh, acc[mf][nf], 0, 0, 0);
        acc[mf][nf] = __builtin_amdgcn_mfma_f32_16x16x32_bf16(ah[mf],  bl, acc[mf][nf], 0, 0, 0);
        acc[mf][nf] = __builtin_amdgcn_mfma_f32_16x16x32_bf16(alv[mf], bh, acc[mf][nf], 0, 0, 0);
      }
    }
    __syncthreads();
  }

  if (DIVN) {
    u32* Cp = (u32*)Cout;
    #pragma unroll
    for (int nf = 0; nf < 4; ++nf) {
      int n = n0 + wc * 64 + nf * 16 + li;
      float invn = 1.0f / normv[n];
      #pragma unroll
      for (int mf = 0; mf < 4; ++mf) {
        int m = m0 + wr * 64 + mf * 16 + kq * 4;
        #pragma unroll
        for (int rr = 0; rr < 4; ++rr) {
          float sc = acc[mf][nf][rr] * invn;
          u32 h = bf16rn(sc);
          u32 lo = bf16rn(sc - bf16f(h));
          Cp[(u32)(m + rr) * (u32)ldc + n] = (h << 16) | lo;
        }
      }
    }
  } else {
    float* Cf = (float*)Cout + (size_t)blockIdx.z * czStride;
    #pragma unroll
    for (int nf = 0; nf < 4; ++nf) {
      int n = n0 + wc * 64 + nf * 16 + li;
      if (n < Nlim) {
        #pragma unroll
        for (int mf = 0; mf < 4; ++mf) {
          int m = m0 + wr * 64 + mf * 16 + kq * 4;
          #pragma unroll
          for (int rr = 0; rr < 4; ++rr)
            Cf[(u32)(m + rr) * (u32)ldc + n] = acc[mf][nf][rr];
        }
      }
    }
  }
}

// ---------- softmax + argmax (top-2, rescue flagging) ----------
__global__ __launch_bounds__(256) void k_softmax(u32* __restrict__ score, float* __restrict__ offs,
                                                 int* __restrict__ rlist, int* __restrict__ rcount) {
  int q = blockIdx.x;
  u32* row = score + (size_t)q * L_;
  int tid = threadIdx.x;
  int wid = tid >> 6, lane = tid & 63;
  __shared__ float smax[4]; __shared__ int sidx[4]; __shared__ float smax2[4]; __shared__ float ssum[4];

  float v[16];
  float v1 = -3.4e38f, v2 = -3.4e38f; int i1 = 0;
  #pragma unroll
  for (int i = 0; i < 16; ++i) {
    int idx = tid + i * 256;
    u32 w = row[idx];
    v[i] = bf16f(w >> 16) + bf16f(w & 0xffffu);
    if (v[i] > v1 || (v[i] == v1 && idx < i1)) { v2 = v1; v1 = v[i]; i1 = idx; }
    else if (v[i] > v2) v2 = v[i];
  }
  #pragma unroll
  for (int off = 32; off; off >>= 1) {
    float ov1 = __shfl_down(v1, off);
    int   oi1 = __shfl_down(i1, off);
    float ov2 = __shfl_down(v2, off);
    if (ov1 > v1 || (ov1 == v1 && oi1 < i1)) { v2 = fmaxf(fmaxf(v2, ov2), v1); v1 = ov1; i1 = oi1; }
    else v2 = fmaxf(fmaxf(v2, ov2), ov1);
  }
  if (lane == 0) { smax[wid] = v1; sidx[wid] = i1; smax2[wid] = v2; }
  __syncthreads();
  if (tid == 0) {
    v1 = smax[0]; i1 = sidx[0]; v2 = smax2[0];
    for (int w = 1; w < 4; ++w) {
      if (smax[w] > v1 || (smax[w] == v1 && sidx[w] < i1)) {
        v2 = fmaxf(fmaxf(v2, smax2[w]), v1); v1 = smax[w]; i1 = sidx[w];
      } else v2 = fmaxf(fmaxf(v2, smax2[w]), smax[w]);
    }
    smax[0] = v1; sidx[0] = i1;
    if (v1 - v2 <= TAU) {
      int pos = atomicAdd(rcount, 1);
      if (pos < 4096) rlist[pos] = q;
    }
  }
  __syncthreads();
  float vmax = smax[0];

  float s = 0.f;
  #pragma unroll
  for (int i = 0; i < 16; ++i) { v[i] = expf((v[i] - vmax) * SCALE); s += v[i]; }
  #pragma unroll
  for (int off = 32; off; off >>= 1) s += __shfl_down(s, off);
  if (lane == 0) ssum[wid] = s;
  __syncthreads();
  if (tid == 0) ssum[0] = ssum[0] + ssum[1] + ssum[2] + ssum[3];
  __syncthreads();
  float inv = 1.f / ssum[0];
  #pragma unroll
  for (int i = 0; i < 16; ++i) {
    float a = v[i] * inv;
    u32 h = bf16rn(a);
    u32 lo = bf16rn(a - bf16f(h));
    row[tid + i * 256] = (h << 16) | lo;
  }
  if (tid == 0) offs[q] = (float)sidx[0];
}

// ---------- exact f64 argmax rescue for flagged rows ----------
__global__ __launch_bounds__(256) void k_rescue(const int* __restrict__ rlist, const int* __restrict__ rcount,
                                                const float* __restrict__ b0, const float* __restrict__ m0,
                                                const float* __restrict__ fmb, float* __restrict__ offs) {
  __shared__ float fp_lds[D_];
  __shared__ double rbest[4]; __shared__ int ridx[4];
  int cnt = *rcount; if (cnt > 4096) cnt = 4096;
  int tid = threadIdx.x;
  int wid = tid >> 6, lane = tid & 63;

  for (int e = blockIdx.x; e < cnt; e += gridDim.x) {
    int q = rlist[e];
    int qy = q >> 6, qx = q & 63;
    for (int d = tid; d < D_; d += 256) {
      int c = d / 9, t = d - c * 9;
      int i = t / 3, j = t - i * 3;
      int yy = qy + i - 1, xx = qx + j - 1;
      float fv = 0.f;
      if ((unsigned)yy < 64u && (unsigned)xx < 64u) fv = fmb[(c << 12) + (yy << 6) + xx];
      fp_lds[d] = fv;
    }
    __syncthreads();

    double bv = -1e300; int bi = 0;
    for (int li = 0; li < 16; ++li) {
      int l = tid + li * 256;
      int ly = l >> 6, lx = l & 63;
      double dot = 0.0, ss = 0.0;
      #pragma unroll
      for (int t = 0; t < 9; ++t) {
        int i = t / 3, j = t - (t / 3) * 3;
        int yy = ly + i - 1, xx = lx + j - 1;
        if ((unsigned)yy < 64u && (unsigned)xx < 64u) {
          float m0v = m0[l * 9 + t];
          int off = (yy << 6) + xx;
          for (int c = 0; c < 64; ++c) {
            float wv = b0[(c << 12) + off] * m0v;     // f32 product, as reference
            float fpv = fp_lds[c * 9 + t];
            dot += (double)wv * (double)fpv;
            ss  += (double)wv * (double)wv;
          }
        }
      }
      double sc = dot / sqrt(ss + (double)EPS);
      if (sc > bv) { bv = sc; bi = l; }
    }
    #pragma unroll
    for (int off = 32; off; off >>= 1) {
      double ov = __shfl_down(bv, off);
      int    oi = __shfl_down(bi, off);
      if (ov > bv || (ov == bv && oi < bi)) { bv = ov; bi = oi; }
    }
    if (lane == 0) { rbest[wid] = bv; ridx[wid] = bi; }
    __syncthreads();
    if (tid == 0) {
      bv = rbest[0]; bi = ridx[0];
      for (int w = 1; w < 4; ++w)
        if (rbest[w] > bv || (rbest[w] == bv && ridx[w] < bi)) { bv = rbest[w]; bi = ridx[w]; }
      offs[q] = (float)bi;
    }
    __syncthreads();
  }
}

// ---------- fold: y[c,p] = sum over 9 taps x 4 K-parts ----------
__global__ __launch_bounds__(256) void k_fold(const float* __restrict__ Gp, float* __restrict__ yout) {
  int idx = blockIdx.x * 256 + threadIdx.x;   // c*4096 + p
  int c = idx >> 12, p = idx & 4095;
  int yy = p >> 6, xx = p & 63;
  float s = 0.f;
  #pragma unroll
  for (int t = 0; t < 9; ++t) {
    int i = t / 3, j = t - (t / 3) * 3;
    int qy = yy + 1 - i, qx = xx + 1 - j;
    if ((unsigned)qy < 64u && (unsigned)qx < 64u) {
      u32 base = (u32)((qy << 6) + qx) * D_ + c * 9 + t;
      #pragma unroll
      for (int z = 0; z < 4; ++z) s += Gp[(size_t)z * 2359296 + base];
    }
  }
  yout[idx] = s;
}

extern "C" void kernel_launch(void* const* d_in, const int* in_sizes, int n_in,
                              void* d_out, int out_size, void* d_ws, size_t ws_size,
                              hipStream_t stream) {
  const float* b_in = (const float*)d_in[0];
  const float* f_in = (const float*)d_in[1];
  const float* mask = (const float*)d_in[2];
  float* out = (float*)d_out;

  char* ws = (char*)d_ws;
  float* mp     = (float*)(ws + 0);
  float* m0buf  = (float*)(ws + 65536);
  float* fm     = (float*)(ws + 212992);
  float* normv  = (float*)(ws + 4407296);
  u16*   w_hi   = (u16*)(ws + 4423680);
  u16*   w_lo   = (u16*)(ws + 9142272);
  u16*   fp_hi  = (u16*)(ws + 13860864);
  u16*   fp_lo  = (u16*)(ws + 18579456);
  u16*   wT_hi  = (u16*)(ws + 23298048);
  u16*   wT_lo  = (u16*)(ws + 28540928);
  u32*   scoreP = (u32*)(ws + 33783808);
  float* Gpart  = (float*)(ws + 100892672);   // 4 x 4096 x 576 f32
  int*   rcount = (int*)(ws + 138641408);
  int*   rlist  = (int*)(ws + 138641664);     // 4096 ints

  k_mp<<<64, 256, 0, stream>>>(mask, mp);
  k_m0<<<144, 256, 0, stream>>>(mp, m0buf);
  k_fm<<<4096, 256, 0, stream>>>(f_in, mp, fm);

  for (int b = 0; b < B_; ++b) {
    const float* bimg = b_in + (size_t)b * C_ * HW;
    const float* fmb  = fm + (size_t)b * C_ * HW;
    float* offs_b = out + (size_t)B_ * C_ * HW + (size_t)b * HW;

    hipMemsetAsync(rcount, 0, 4, stream);
    k_patch<<<9216, 256, 0, stream>>>(bimg, m0buf, w_hi, w_lo);
    k_norm<<<1024, 256, 0, stream>>>(w_hi, w_lo, normv);
    k_patchT<<<10240, 256, 0, stream>>>(bimg, m0buf, wT_hi, wT_lo);
    k_patch<<<9216, 256, 0, stream>>>(fmb, nullptr, fp_hi, fp_lo);
    // GEMM1: score[q,l] = fp.w / norm  -> packed u32
    k_mfma<false, true><<<dim3(32, 32, 1), 256, 0, stream>>>(
        fp_hi, fp_lo, w_hi, w_lo, normv, scoreP,
        D_, D_, L_, L_, 0, 18, 0);
    k_softmax<<<4096, 256, 0, stream>>>(scoreP, offs_b, rlist, rcount);
    // GEMM2: G[q,d] = attn.wT, split-K=4 partials
    k_mfma<true, false><<<dim3(5, 32, 4), 256, 0, stream>>>(
        scoreP, nullptr, wT_hi, wT_lo, nullptr, Gpart,
        L_, L_, D_, D_, 1024, 32, 2359296);
    k_rescue<<<256, 256, 0, stream>>>(rlist, rcount, bimg, m0buf, fmb, offs_b);
    k_fold<<<1024, 256, 0, stream>>>(Gpart, out + (size_t)b * C_ * HW);
  }
}

// Round 4
// 1128.202 us; speedup vs baseline: 4.7567x; 4.7567x over previous
//
#include <hip/hip_runtime.h>
#include <math.h>

typedef unsigned int u32;
typedef unsigned short u16;
typedef unsigned long long u64;
typedef short s8v __attribute__((ext_vector_type(8)));
typedef float f4v __attribute__((ext_vector_type(4)));
typedef u32 u4v __attribute__((ext_vector_type(4)));

#define B_ 4
#define C_ 64
#define HW 4096
#define L_ 4096
#define D_ 576
#define MW 256
#define SCALE 10.0f
#define EPS 1e-4f
#define TAU 0.015f
#define PAIRCAP 262144

__device__ __forceinline__ u32 bf16rn(float x) {
  u32 u = __float_as_uint(x);
  return (u + 0x7fffu + ((u >> 16) & 1u)) >> 16;
}
__device__ __forceinline__ float bf16f(u32 h) { return __uint_as_float(h << 16); }

__device__ __forceinline__ void gld16(const void* g, void* l) {
  __builtin_amdgcn_global_load_lds((const __attribute__((address_space(1))) void*)g,
                                   (__attribute__((address_space(3))) void*)l, 16, 0, 0);
}

// ---------- small prep kernels ----------
__global__ __launch_bounds__(256) void k_mp(const float* __restrict__ mask, float* __restrict__ mp) {
  int idx = blockIdx.x * 256 + threadIdx.x;
  int b = idx >> 12, p = idx & 4095;
  int y = p >> 6, x = p & 63;
  const float* mb = mask + (size_t)b * MW * MW;
  float s = 0.f;
  #pragma unroll
  for (int i = 0; i < 4; ++i)
    #pragma unroll
    for (int j = 0; j < 4; ++j)
      s += mb[(y * 4 + i) * MW + x * 4 + j];
  mp[idx] = s * (1.f / 16.f);
}

__global__ __launch_bounds__(256) void k_m0(const float* __restrict__ mp, float* __restrict__ m0) {
  int idx = blockIdx.x * 256 + threadIdx.x;   // l*9 + t
  int l = idx / 9, t = idx - l * 9;
  int ly = l >> 6, lx = l & 63;
  int i = t / 3, j = t - i * 3;
  int yy = ly + i - 1, xx = lx + j - 1;
  float v = 0.f;
  if ((unsigned)yy < 64u && (unsigned)xx < 64u) v = mp[(yy << 6) + xx];
  m0[idx] = v;
}

__global__ __launch_bounds__(256) void k_fm(const float* __restrict__ f, const float* __restrict__ mp,
                                            float* __restrict__ fm) {
  int idx = blockIdx.x * 256 + threadIdx.x;
  int p = idx & 4095;
  int b = idx >> 18;
  fm[idx] = f[idx] * (1.f - mp[(b << 12) + p]);
}

// patches row-major [l][576] -> hi/lo bf16 planes
__global__ __launch_bounds__(256) void k_patch(const float* __restrict__ img,
                                               const float* __restrict__ m0,
                                               u16* __restrict__ oh, u16* __restrict__ ol) {
  int idx = blockIdx.x * 256 + threadIdx.x;   // l*576 + d
  int l = idx / D_;
  int d = idx - l * D_;
  int c = d / 9, t = d - c * 9;
  int ly = l >> 6, lx = l & 63;
  int i = t / 3, j = t - i * 3;
  int yy = ly + i - 1, xx = lx + j - 1;
  float v = 0.f;
  if ((unsigned)yy < 64u && (unsigned)xx < 64u) v = img[(c << 12) + (yy << 6) + xx];
  if (m0) v *= m0[l * 9 + t];
  u32 h = bf16rn(v);
  oh[idx] = (u16)h;
  ol[idx] = (u16)bf16rn(v - bf16f(h));
}

// transposed patches [d<640][4096 l] -> hi/lo bf16 (rows 576..639 zeroed)
__global__ __launch_bounds__(256) void k_patchT(const float* __restrict__ img,
                                                const float* __restrict__ m0,
                                                u16* __restrict__ oh, u16* __restrict__ ol) {
  int idx = blockIdx.x * 256 + threadIdx.x;   // d*4096 + l
  int d = idx >> 12, l = idx & 4095;
  float v = 0.f;
  if (d < D_) {
    int c = d / 9, t = d - c * 9;
    int ly = l >> 6, lx = l & 63;
    int i = t / 3, j = t - i * 3;
    int yy = ly + i - 1, xx = lx + j - 1;
    if ((unsigned)yy < 64u && (unsigned)xx < 64u)
      v = img[(c << 12) + (yy << 6) + xx] * m0[l * 9 + t];
  }
  u32 h = bf16rn(v);
  oh[idx] = (u16)h;
  ol[idx] = (u16)bf16rn(v - bf16f(h));
}

__global__ __launch_bounds__(256) void k_norm(const u16* __restrict__ wh, const u16* __restrict__ wl,
                                              float* __restrict__ normv) {
  int l = blockIdx.x * 4 + (threadIdx.x >> 6);
  int lane = threadIdx.x & 63;
  const u16* rh = wh + (size_t)l * D_;
  const u16* rl = wl + (size_t)l * D_;
  float s = 0.f;
  for (int i = lane; i < D_; i += 64) {
    float v = bf16f(rh[i]) + bf16f(rl[i]);
    s += v * v;
  }
  #pragma unroll
  for (int off = 32; off; off >>= 1) s += __shfl_down(s, off);
  if (lane == 0) normv[l] = sqrtf(s + EPS);
}

// exact f64 norm per l: norme[l] = sqrt(sum (b0*m0)^2 + eps)
__global__ __launch_bounds__(256) void k_norme(const float* __restrict__ b0, const float* __restrict__ m0,
                                               double* __restrict__ norme) {
  int l = blockIdx.x * 4 + (threadIdx.x >> 6);
  int lane = threadIdx.x & 63;
  int ly = l >> 6, lx = l & 63;
  double s = 0.0;
  for (int i = lane; i < D_; i += 64) {
    int c = i / 9, t = i - c * 9;
    int ii = t / 3, jj = t - ii * 3;
    int yy = ly + ii - 1, xx = lx + jj - 1;
    if ((unsigned)yy < 64u && (unsigned)xx < 64u) {
      float wv = b0[(c << 12) + (yy << 6) + xx] * m0[l * 9 + t];
      s += (double)wv * (double)wv;
    }
  }
  #pragma unroll
  for (int off = 32; off; off >>= 1) s += __shfl_down(s, off);
  if (lane == 0) norme[l] = sqrt(s + (double)EPS);
}

// ---------- MFMA split-bf16 GEMM ----------
template<bool PACKED_A, bool DIVN>
__global__ __launch_bounds__(256) void k_mfma(
    const void* __restrict__ Ah_, const u16* __restrict__ Al,
    const u16* __restrict__ Bh, const u16* __restrict__ Bl,
    const float* __restrict__ normv, void* __restrict__ Cout,
    int lda, int ldb, int ldc, int Nlim, int kPerZ, int nChunks, int czStride)
{
  __shared__ u32 lds[8192];
  u16* ldsu = (u16*)lds;
  const int tid = threadIdx.x;
  const int lane = tid & 63, wid = tid >> 6;
  const int wr = wid >> 1, wc = wid & 1;
  const int kq = lane >> 4, li = lane & 15;

  int nwg = gridDim.x * gridDim.y;
  int bid = blockIdx.y * gridDim.x + blockIdx.x;
  int cpx = nwg >> 3;
  int swz = (bid & 7) * cpx + (bid >> 3);
  int bx = swz % gridDim.x, by = swz / gridDim.x;
  const int m0 = by * 128, n0 = bx * 128;
  const int kz = blockIdx.z * kPerZ;

  f4v acc[4][4] = {};

  for (int kc = 0; kc < nChunks; ++kc) {
    int k0 = kz + kc * 32;
    if (PACKED_A) {
      const u32* Ap = (const u32*)Ah_;
      #pragma unroll
      for (int i = 0; i < 4; ++i) {
        int s = tid + i * 256;
        int r = s >> 3, ks = s & 7;
        int kg = ks ^ (r & 7);
        gld16(Ap + (u32)(m0 + r) * (u32)lda + (u32)(k0 + kg * 4), (char*)lds + s * 16);
      }
    } else {
      const u16* Ahp = (const u16*)Ah_;
      #pragma unroll
      for (int i = 0; i < 2; ++i) {
        int s = tid + i * 256;
        int r = s >> 2, ks = s & 3;
        int kg = ks ^ ((r >> 1) & 3);
        u32 go = (u32)(m0 + r) * (u32)lda + (u32)(k0 + kg * 8);
        gld16(Ahp + go, (char*)lds + s * 16);
        gld16(Al + go, (char*)lds + 8192 + s * 16);
      }
    }
    #pragma unroll
    for (int i = 0; i < 2; ++i) {
      int s = tid + i * 256;
      int r = s >> 2, ks = s & 3;
      int kg = ks ^ ((r >> 1) & 3);
      u32 go = (u32)(n0 + r) * (u32)ldb + (u32)(k0 + kg * 8);
      gld16(Bh + go, (char*)lds + 16384 + s * 16);
      gld16(Bl + go, (char*)lds + 24576 + s * 16);
    }
    __syncthreads();

    s8v ah[4], alv[4];
    if (PACKED_A) {
      #pragma unroll
      for (int mf = 0; mf < 4; ++mf) {
        int r = wr * 64 + mf * 16 + li;
        int rb = r * 32, sw = r & 7;
        u4v p0 = *(const u4v*)&lds[rb + (((kq * 2 + 0) ^ sw) << 2)];
        u4v p1 = *(const u4v*)&lds[rb + (((kq * 2 + 1) ^ sw) << 2)];
        s8v h = { (short)(p0[0] >> 16), (short)(p0[1] >> 16), (short)(p0[2] >> 16), (short)(p0[3] >> 16),
                  (short)(p1[0] >> 16), (short)(p1[1] >> 16), (short)(p1[2] >> 16), (short)(p1[3] >> 16) };
        s8v lo = { (short)p0[0], (short)p0[1], (short)p0[2], (short)p0[3],
                   (short)p1[0], (short)p1[1], (short)p1[2], (short)p1[3] };
        ah[mf] = h; alv[mf] = lo;
      }
    } else {
      #pragma unroll
      for (int mf = 0; mf < 4; ++mf) {
        int r = wr * 64 + mf * 16 + li;
        int off = r * 32 + (kq ^ ((r >> 1) & 3)) * 8;
        ah[mf]  = *(const s8v*)&ldsu[off];
        alv[mf] = *(const s8v*)&ldsu[4096 + off];
      }
    }
    #pragma unroll
    for (int nf = 0; nf < 4; ++nf) {
      int r = wc * 64 + nf * 16 + li;
      int off = r * 32 + (kq ^ ((r >> 1) & 3)) * 8;
      s8v bh = *(const s8v*)&ldsu[8192 + off];
      s8v bl = *(const s8v*)&ldsu[12288 + off];
      #pragma unroll
      for (int mf = 0; mf < 4; ++mf) {
        acc[mf][nf] = __builtin_amdgcn_mfma_f32_16x16x32_bf16(ah[mf],  bh, acc[mf][nf], 0, 0, 0);
        acc[mf][nf] = __builtin_amdgcn_mfma_f32_16x16x32_bf16(ah[mf],  bl, acc[mf][nf], 0, 0, 0);
        acc[mf][nf] = __builtin_amdgcn_mfma_f32_16x16x32_bf16(alv[mf], bh, acc[mf][nf], 0, 0, 0);
      }
    }
    __syncthreads();
  }

  if (DIVN) {
    u32* Cp = (u32*)Cout;
    #pragma unroll
    for (int nf = 0; nf < 4; ++nf) {
      int n = n0 + wc * 64 + nf * 16 + li;
      float invn = 1.0f / normv[n];
      #pragma unroll
      for (int mf = 0; mf < 4; ++mf) {
        int m = m0 + wr * 64 + mf * 16 + kq * 4;
        #pragma unroll
        for (int rr = 0; rr < 4; ++rr) {
          float sc = acc[mf][nf][rr] * invn;
          u32 h = bf16rn(sc);
          u32 lo = bf16rn(sc - bf16f(h));
          Cp[(u32)(m + rr) * (u32)ldc + n] = (h << 16) | lo;
        }
      }
    }
  } else {
    float* Cf = (float*)Cout + (size_t)blockIdx.z * czStride;
    #pragma unroll
    for (int nf = 0; nf < 4; ++nf) {
      int n = n0 + wc * 64 + nf * 16 + li;
      if (n < Nlim) {
        #pragma unroll
        for (int mf = 0; mf < 4; ++mf) {
          int m = m0 + wr * 64 + mf * 16 + kq * 4;
          #pragma unroll
          for (int rr = 0; rr < 4; ++rr)
            Cf[(u32)(m + rr) * (u32)ldc + n] = acc[mf][nf][rr];
        }
      }
    }
  }
}

// ---------- softmax + argmax (top-2 flag + candidate-pair emission) ----------
__global__ __launch_bounds__(256) void k_softmax(u32* __restrict__ score, float* __restrict__ offs,
                                                 int* __restrict__ rlist, int* __restrict__ rcount,
                                                 u32* __restrict__ pairs, int* __restrict__ pcount) {
  int q = blockIdx.x;
  u32* row = score + (size_t)q * L_;
  int tid = threadIdx.x;
  int wid = tid >> 6, lane = tid & 63;
  __shared__ float smax[4]; __shared__ int sidx[4]; __shared__ float smax2[4]; __shared__ float ssum[4];
  __shared__ int sflag;

  float v[16];
  float v1 = -3.4e38f, v2 = -3.4e38f; int i1 = 0;
  #pragma unroll
  for (int i = 0; i < 16; ++i) {
    int idx = tid + i * 256;
    u32 w = row[idx];
    v[i] = bf16f(w >> 16) + bf16f(w & 0xffffu);
    if (v[i] > v1 || (v[i] == v1 && idx < i1)) { v2 = v1; v1 = v[i]; i1 = idx; }
    else if (v[i] > v2) v2 = v[i];
  }
  #pragma unroll
  for (int off = 32; off; off >>= 1) {
    float ov1 = __shfl_down(v1, off);
    int   oi1 = __shfl_down(i1, off);
    float ov2 = __shfl_down(v2, off);
    if (ov1 > v1 || (ov1 == v1 && oi1 < i1)) { v2 = fmaxf(fmaxf(v2, ov2), v1); v1 = ov1; i1 = oi1; }
    else v2 = fmaxf(fmaxf(v2, ov2), ov1);
  }
  if (lane == 0) { smax[wid] = v1; sidx[wid] = i1; smax2[wid] = v2; }
  __syncthreads();
  if (tid == 0) {
    v1 = smax[0]; i1 = sidx[0]; v2 = smax2[0];
    for (int w = 1; w < 4; ++w) {
      if (smax[w] > v1 || (smax[w] == v1 && sidx[w] < i1)) {
        v2 = fmaxf(fmaxf(v2, smax2[w]), v1); v1 = smax[w]; i1 = sidx[w];
      } else v2 = fmaxf(fmaxf(v2, smax2[w]), smax[w]);
    }
    smax[0] = v1; sidx[0] = i1;
    sflag = (v1 - v2 <= TAU) ? 1 : 0;
    if (sflag) {
      int pos = atomicAdd(rcount, 1);
      if (pos < 4096) rlist[pos] = q;
    }
  }
  __syncthreads();
  float vmax = smax[0];

  // candidate emission for flagged rows (before v[] is overwritten by exp)
  if (sflag) {
    float thr = vmax - 2.0f * TAU;
    #pragma unroll
    for (int i = 0; i < 16; ++i) {
      if (v[i] >= thr) {
        int pos = atomicAdd(pcount, 1);
        if (pos < PAIRCAP) pairs[pos] = ((u32)q << 12) | (u32)(tid + i * 256);
      }
    }
  }

  float s = 0.f;
  #pragma unroll
  for (int i = 0; i < 16; ++i) { v[i] = expf((v[i] - vmax) * SCALE); s += v[i]; }
  #pragma unroll
  for (int off = 32; off; off >>= 1) s += __shfl_down(s, off);
  if (lane == 0) ssum[wid] = s;
  __syncthreads();
  if (tid == 0) ssum[0] = ssum[0] + ssum[1] + ssum[2] + ssum[3];
  __syncthreads();
  float inv = 1.f / ssum[0];
  #pragma unroll
  for (int i = 0; i < 16; ++i) {
    float a = v[i] * inv;
    u32 h = bf16rn(a);
    u32 lo = bf16rn(a - bf16f(h));
    row[tid + i * 256] = (h << 16) | lo;
  }
  if (tid == 0) offs[q] = (float)sidx[0];
}

// ---------- f64 rescue: one wave per (q,l) pair ----------
__global__ __launch_bounds__(256) void k_rpairs(const u32* __restrict__ pairs, const int* __restrict__ pcount,
                                                const float* __restrict__ b0, const float* __restrict__ m0,
                                                const float* __restrict__ fmb, const double* __restrict__ norme,
                                                u64* __restrict__ rbest) {
  int nw = gridDim.x * 4;
  int gw = blockIdx.x * 4 + (threadIdx.x >> 6);
  int lane = threadIdx.x & 63;
  int cnt = *pcount; if (cnt > PAIRCAP) cnt = PAIRCAP;
  for (int e = gw; e < cnt; e += nw) {
    u32 pr = pairs[e];
    int q = pr >> 12, l = pr & 4095;
    int qy = q >> 6, qx = q & 63, ly = l >> 6, lx = l & 63;
    int c = lane;
    double dot = 0.0;
    #pragma unroll
    for (int t = 0; t < 9; ++t) {
      int i = t / 3, j = t - (t / 3) * 3;
      int wy = ly + i - 1, wx = lx + j - 1;
      int fy = qy + i - 1, fx = qx + j - 1;
      float wv = 0.f, fv = 0.f;
      if ((unsigned)wy < 64u && (unsigned)wx < 64u) wv = b0[(c << 12) + (wy << 6) + wx] * m0[l * 9 + t];
      if ((unsigned)fy < 64u && (unsigned)fx < 64u) fv = fmb[(c << 12) + (fy << 6) + fx];
      dot += (double)wv * (double)fv;
    }
    #pragma unroll
    for (int off = 32; off; off >>= 1) dot += __shfl_down(dot, off);
    if (lane == 0) {
      double sc = dot / norme[l];
      u64 bbits = (u64)__double_as_longlong(sc);
      if (bbits >> 63) bbits = ~bbits; else bbits |= 0x8000000000000000ull;
      u64 key = (bbits & ~0xFFFull) | (u64)(4095 - l);
      atomicMax(rbest + q, key);
    }
  }
}

__global__ __launch_bounds__(256) void k_rfin(const int* __restrict__ rlist, const int* __restrict__ rcount,
                                              const u64* __restrict__ rbest, float* __restrict__ offs) {
  int cnt = *rcount; if (cnt > 4096) cnt = 4096;
  for (int e = blockIdx.x * 256 + threadIdx.x; e < cnt; e += gridDim.x * 256) {
    int q = rlist[e];
    offs[q] = (float)(4095 - (int)(rbest[q] & 0xFFFull));
  }
}

// ---------- fold: y[c,p] = sum over 9 taps x 4 K-parts ----------
__global__ __launch_bounds__(256) void k_fold(const float* __restrict__ Gp, float* __restrict__ yout) {
  int idx = blockIdx.x * 256 + threadIdx.x;   // c*4096 + p
  int c = idx >> 12, p = idx & 4095;
  int yy = p >> 6, xx = p & 63;
  float s = 0.f;
  #pragma unroll
  for (int t = 0; t < 9; ++t) {
    int i = t / 3, j = t - (t / 3) * 3;
    int qy = yy + 1 - i, qx = xx + 1 - j;
    if ((unsigned)qy < 64u && (unsigned)qx < 64u) {
      u32 base = (u32)((qy << 6) + qx) * D_ + c * 9 + t;
      #pragma unroll
      for (int z = 0; z < 4; ++z) s += Gp[(size_t)z * 2359296 + base];
    }
  }
  yout[idx] = s;
}

extern "C" void kernel_launch(void* const* d_in, const int* in_sizes, int n_in,
                              void* d_out, int out_size, void* d_ws, size_t ws_size,
                              hipStream_t stream) {
  const float* b_in = (const float*)d_in[0];
  const float* f_in = (const float*)d_in[1];
  const float* mask = (const float*)d_in[2];
  float* out = (float*)d_out;

  char* ws = (char*)d_ws;
  float* mp     = (float*)(ws + 0);
  float* m0buf  = (float*)(ws + 65536);
  float* fm     = (float*)(ws + 212992);
  float* normv  = (float*)(ws + 4407296);
  u16*   w_hi   = (u16*)(ws + 4423680);
  u16*   w_lo   = (u16*)(ws + 9142272);
  u16*   fp_hi  = (u16*)(ws + 13860864);
  u16*   fp_lo  = (u16*)(ws + 18579456);
  u16*   wT_hi  = (u16*)(ws + 23298048);
  u16*   wT_lo  = (u16*)(ws + 28540928);
  u32*   scoreP = (u32*)(ws + 33783808);
  float* Gpart  = (float*)(ws + 100892672);   // 4 x 4096 x 576 f32 -> ends 138641408
  int*   rcount = (int*)(ws + 138641408);
  int*   pcount = (int*)(ws + 138641412);
  int*   rlist  = (int*)(ws + 138641664);     // 4096 ints -> ends 138657920
  double* norme = (double*)(ws + 138657920);  // 4096 f64  -> ends 138690688
  u64*   rbest  = (u64*)(ws + 138690688);     // 4096 u64  -> ends 138723456
  u32*   pairs  = (u32*)(ws + 138723456);     // 262144 u32 -> ends 139771904

  k_mp<<<64, 256, 0, stream>>>(mask, mp);
  k_m0<<<144, 256, 0, stream>>>(mp, m0buf);
  k_fm<<<4096, 256, 0, stream>>>(f_in, mp, fm);

  for (int b = 0; b < B_; ++b) {
    const float* bimg = b_in + (size_t)b * C_ * HW;
    const float* fmb  = fm + (size_t)b * C_ * HW;
    float* offs_b = out + (size_t)B_ * C_ * HW + (size_t)b * HW;

    hipMemsetAsync(rcount, 0, 8, stream);                 // rcount + pcount
    hipMemsetAsync(rbest, 0, 4096 * sizeof(u64), stream);
    k_patch<<<9216, 256, 0, stream>>>(bimg, m0buf, w_hi, w_lo);
    k_norm<<<1024, 256, 0, stream>>>(w_hi, w_lo, normv);
    k_norme<<<1024, 256, 0, stream>>>(bimg, m0buf, norme);
    k_patchT<<<10240, 256, 0, stream>>>(bimg, m0buf, wT_hi, wT_lo);
    k_patch<<<9216, 256, 0, stream>>>(fmb, nullptr, fp_hi, fp_lo);
    // GEMM1: score[q,l] = fp.w / norm  -> packed u32
    k_mfma<false, true><<<dim3(32, 32, 1), 256, 0, stream>>>(
        fp_hi, fp_lo, w_hi, w_lo, normv, scoreP,
        D_, D_, L_, L_, 0, 18, 0);
    k_softmax<<<4096, 256, 0, stream>>>(scoreP, offs_b, rlist, rcount, pairs, pcount);
    // GEMM2: G[q,d] = attn.wT, split-K=4 partials
    k_mfma<true, false><<<dim3(5, 32, 4), 256, 0, stream>>>(
        scoreP, nullptr, wT_hi, wT_lo, nullptr, Gpart,
        L_, L_, D_, D_, 1024, 32, 2359296);
    k_rpairs<<<512, 256, 0, stream>>>(pairs, pcount, bimg, m0buf, fmb, norme, rbest);
    k_rfin<<<16, 256, 0, stream>>>(rlist, rcount, rbest, offs_b);
    k_fold<<<1024, 256, 0, stream>>>(Gpart, out + (size_t)b * C_ * HW);
  }
}

// Round 5
// 1012.928 us; speedup vs baseline: 5.2980x; 1.1138x over previous
//
#include <hip/hip_runtime.h>
#include <math.h>

typedef unsigned int u32;
typedef unsigned short u16;
typedef unsigned long long u64;
typedef short s8v __attribute__((ext_vector_type(8)));
typedef float f4v __attribute__((ext_vector_type(4)));
typedef u32 u4v __attribute__((ext_vector_type(4)));

#define B_ 4
#define C_ 64
#define HW 4096
#define L_ 4096
#define D_ 576
#define MW 256
#define SCALE 10.0f
#define EPS 1e-4f
#define TAU 0.015f
#define PAIRCAP 262144

__device__ __forceinline__ u32 bf16rn(float x) {
  u32 u = __float_as_uint(x);
  return (u + 0x7fffu + ((u >> 16) & 1u)) >> 16;
}
__device__ __forceinline__ float bf16f(u32 h) { return __uint_as_float(h << 16); }

__device__ __forceinline__ void gld16(const void* g, void* l) {
  __builtin_amdgcn_global_load_lds((const __attribute__((address_space(1))) void*)g,
                                   (__attribute__((address_space(3))) void*)l, 16, 0, 0);
}

// ---------- small prep kernels ----------
__global__ __launch_bounds__(256) void k_mp(const float* __restrict__ mask, float* __restrict__ mp) {
  int idx = blockIdx.x * 256 + threadIdx.x;
  int b = idx >> 12, p = idx & 4095;
  int y = p >> 6, x = p & 63;
  const float* mb = mask + (size_t)b * MW * MW;
  float s = 0.f;
  #pragma unroll
  for (int i = 0; i < 4; ++i)
    #pragma unroll
    for (int j = 0; j < 4; ++j)
      s += mb[(y * 4 + i) * MW + x * 4 + j];
  mp[idx] = s * (1.f / 16.f);
}

__global__ __launch_bounds__(256) void k_m0(const float* __restrict__ mp, float* __restrict__ m0) {
  int idx = blockIdx.x * 256 + threadIdx.x;   // l*9 + t
  int l = idx / 9, t = idx - l * 9;
  int ly = l >> 6, lx = l & 63;
  int i = t / 3, j = t - i * 3;
  int yy = ly + i - 1, xx = lx + j - 1;
  float v = 0.f;
  if ((unsigned)yy < 64u && (unsigned)xx < 64u) v = mp[(yy << 6) + xx];
  m0[idx] = v;
}

__global__ __launch_bounds__(256) void k_fm(const float* __restrict__ f, const float* __restrict__ mp,
                                            float* __restrict__ fm) {
  int idx = blockIdx.x * 256 + threadIdx.x;
  int p = idx & 4095;
  int b = idx >> 18;
  fm[idx] = f[idx] * (1.f - mp[(b << 12) + p]);
}

// patches row-major [l][576] -> hi/lo bf16 planes
__global__ __launch_bounds__(256) void k_patch(const float* __restrict__ img,
                                               const float* __restrict__ m0,
                                               u16* __restrict__ oh, u16* __restrict__ ol) {
  int idx = blockIdx.x * 256 + threadIdx.x;   // l*576 + d
  int l = idx / D_;
  int d = idx - l * D_;
  int c = d / 9, t = d - c * 9;
  int ly = l >> 6, lx = l & 63;
  int i = t / 3, j = t - i * 3;
  int yy = ly + i - 1, xx = lx + j - 1;
  float v = 0.f;
  if ((unsigned)yy < 64u && (unsigned)xx < 64u) v = img[(c << 12) + (yy << 6) + xx];
  if (m0) v *= m0[l * 9 + t];
  u32 h = bf16rn(v);
  oh[idx] = (u16)h;
  ol[idx] = (u16)bf16rn(v - bf16f(h));
}

// transposed patches [d<640][4096 l] -> hi/lo bf16 (rows 576..639 zeroed)
__global__ __launch_bounds__(256) void k_patchT(const float* __restrict__ img,
                                                const float* __restrict__ m0,
                                                u16* __restrict__ oh, u16* __restrict__ ol) {
  int idx = blockIdx.x * 256 + threadIdx.x;   // d*4096 + l
  int d = idx >> 12, l = idx & 4095;
  float v = 0.f;
  if (d < D_) {
    int c = d / 9, t = d - c * 9;
    int ly = l >> 6, lx = l & 63;
    int i = t / 3, j = t - i * 3;
    int yy = ly + i - 1, xx = lx + j - 1;
    if ((unsigned)yy < 64u && (unsigned)xx < 64u)
      v = img[(c << 12) + (yy << 6) + xx] * m0[l * 9 + t];
  }
  u32 h = bf16rn(v);
  oh[idx] = (u16)h;
  ol[idx] = (u16)bf16rn(v - bf16f(h));
}

__global__ __launch_bounds__(256) void k_norm(const u16* __restrict__ wh, const u16* __restrict__ wl,
                                              float* __restrict__ normv) {
  int l = blockIdx.x * 4 + (threadIdx.x >> 6);
  int lane = threadIdx.x & 63;
  const u16* rh = wh + (size_t)l * D_;
  const u16* rl = wl + (size_t)l * D_;
  float s = 0.f;
  for (int i = lane; i < D_; i += 64) {
    float v = bf16f(rh[i]) + bf16f(rl[i]);
    s += v * v;
  }
  #pragma unroll
  for (int off = 32; off; off >>= 1) s += __shfl_down(s, off);
  if (lane == 0) normv[l] = sqrtf(s + EPS);
}

// exact f64 norm per l
__global__ __launch_bounds__(256) void k_norme(const float* __restrict__ b0, const float* __restrict__ m0,
                                               double* __restrict__ norme) {
  int l = blockIdx.x * 4 + (threadIdx.x >> 6);
  int lane = threadIdx.x & 63;
  int ly = l >> 6, lx = l & 63;
  double s = 0.0;
  for (int i = lane; i < D_; i += 64) {
    int c = i / 9, t = i - c * 9;
    int ii = t / 3, jj = t - ii * 3;
    int yy = ly + ii - 1, xx = lx + jj - 1;
    if ((unsigned)yy < 64u && (unsigned)xx < 64u) {
      float wv = b0[(c << 12) + (yy << 6) + xx] * m0[l * 9 + t];
      s += (double)wv * (double)wv;
    }
  }
  #pragma unroll
  for (int off = 32; off; off >>= 1) s += __shfl_down(s, off);
  if (lane == 0) norme[l] = sqrt(s + (double)EPS);
}

// ---------- MFMA split-bf16 GEMM: block 256x128, 4 waves, per-wave 128x64 ----------
// LDS 48KB: planar A planes @0/@16K, packed A @0(32K); B planes @32K/@40K.
template<bool PACKED_A, bool DIVN>
__global__ __launch_bounds__(256, 2) void k_mfma(
    const void* __restrict__ Ah_, const u16* __restrict__ Al,
    const u16* __restrict__ Bh, const u16* __restrict__ Bl,
    const float* __restrict__ normv, void* __restrict__ Cout,
    int lda, int ldb, int ldc, int Nlim, int kPerZ, int nChunks, int czStride)
{
  __shared__ u32 lds[12288];
  u16* ldsu = (u16*)lds;
  const int tid = threadIdx.x;
  const int lane = tid & 63, wid = tid >> 6;
  const int wrM = wid >> 1, wc = wid & 1;
  const int kq = lane >> 4, li = lane & 15;

  int nwg = gridDim.x * gridDim.y;
  int bid = blockIdx.y * gridDim.x + blockIdx.x;
  int cpx = nwg >> 3;                 // 512 and 80 both divisible by 8
  int swz = (bid & 7) * cpx + (bid >> 3);
  int bx = swz % gridDim.x, by = swz / gridDim.x;
  const int m0 = by * 256, n0 = bx * 128;
  const int kz = blockIdx.z * kPerZ;

  f4v acc[8][4] = {};

  for (int kc = 0; kc < nChunks; ++kc) {
    int k0 = kz + kc * 32;
    if (PACKED_A) {
      const u32* Ap = (const u32*)Ah_;
      #pragma unroll
      for (int i = 0; i < 8; ++i) {
        int s = tid + i * 256;                  // 2048 slots of 16B (256 rows x 128B)
        int r = s >> 3, ks = s & 7;
        int kg = ks ^ (r & 7);
        gld16(Ap + (u32)(m0 + r) * (u32)lda + (u32)(k0 + kg * 4), (char*)lds + s * 16);
      }
    } else {
      const u16* Ahp = (const u16*)Ah_;
      #pragma unroll
      for (int i = 0; i < 4; ++i) {
        int s = tid + i * 256;                  // 1024 slots per plane (256 rows x 64B)
        int r = s >> 2, ks = s & 3;
        int kg = ks ^ ((r >> 1) & 3);
        u32 go = (u32)(m0 + r) * (u32)lda + (u32)(k0 + kg * 8);
        gld16(Ahp + go, (char*)lds + s * 16);
        gld16(Al + go, (char*)lds + 16384 + s * 16);
      }
    }
    #pragma unroll
    for (int i = 0; i < 2; ++i) {
      int s = tid + i * 256;                    // 512 slots per plane (128 rows x 64B)
      int r = s >> 2, ks = s & 3;
      int kg = ks ^ ((r >> 1) & 3);
      u32 go = (u32)(n0 + r) * (u32)ldb + (u32)(k0 + kg * 8);
      gld16(Bh + go, (char*)lds + 32768 + s * 16);
      gld16(Bl + go, (char*)lds + 40960 + s * 16);
    }
    __syncthreads();

    s8v ah[8], alv[8];
    if (PACKED_A) {
      #pragma unroll
      for (int mf = 0; mf < 8; ++mf) {
        int r = wrM * 128 + mf * 16 + li;
        int rb = r * 32, sw = r & 7;
        u4v p0 = *(const u4v*)&lds[rb + (((kq * 2 + 0) ^ sw) << 2)];
        u4v p1 = *(const u4v*)&lds[rb + (((kq * 2 + 1) ^ sw) << 2)];
        s8v h = { (short)(p0[0] >> 16), (short)(p0[1] >> 16), (short)(p0[2] >> 16), (short)(p0[3] >> 16),
                  (short)(p1[0] >> 16), (short)(p1[1] >> 16), (short)(p1[2] >> 16), (short)(p1[3] >> 16) };
        s8v lo = { (short)p0[0], (short)p0[1], (short)p0[2], (short)p0[3],
                   (short)p1[0], (short)p1[1], (short)p1[2], (short)p1[3] };
        ah[mf] = h; alv[mf] = lo;
      }
    } else {
      #pragma unroll
      for (int mf = 0; mf < 8; ++mf) {
        int r = wrM * 128 + mf * 16 + li;
        int off = r * 32 + (kq ^ ((r >> 1) & 3)) * 8;
        ah[mf]  = *(const s8v*)&ldsu[off];
        alv[mf] = *(const s8v*)&ldsu[8192 + off];
      }
    }
    #pragma unroll
    for (int nf = 0; nf < 4; ++nf) {
      int r = wc * 64 + nf * 16 + li;
      int off = r * 32 + (kq ^ ((r >> 1) & 3)) * 8;
      s8v bh = *(const s8v*)&ldsu[16384 + off];
      s8v bl = *(const s8v*)&ldsu[20480 + off];
      #pragma unroll
      for (int mf = 0; mf < 8; ++mf) {
        acc[mf][nf] = __builtin_amdgcn_mfma_f32_16x16x32_bf16(ah[mf],  bh, acc[mf][nf], 0, 0, 0);
        acc[mf][nf] = __builtin_amdgcn_mfma_f32_16x16x32_bf16(ah[mf],  bl, acc[mf][nf], 0, 0, 0);
        acc[mf][nf] = __builtin_amdgcn_mfma_f32_16x16x32_bf16(alv[mf], bh, acc[mf][nf], 0, 0, 0);
      }
    }
    __syncthreads();
  }

  if (DIVN) {
    u32* Cp = (u32*)Cout;
    #pragma unroll
    for (int nf = 0; nf < 4; ++nf) {
      int n = n0 + wc * 64 + nf * 16 + li;
      float invn = 1.0f / normv[n];
      #pragma unroll
      for (int mf = 0; mf < 8; ++mf) {
        int m = m0 + wrM * 128 + mf * 16 + kq * 4;
        #pragma unroll
        for (int rr = 0; rr < 4; ++rr) {
          float sc = acc[mf][nf][rr] * invn;
          u32 h = bf16rn(sc);
          u32 lo = bf16rn(sc - bf16f(h));
          Cp[(u32)(m + rr) * (u32)ldc + n] = (h << 16) | lo;
        }
      }
    }
  } else {
    float* Cf = (float*)Cout + (size_t)blockIdx.z * czStride;
    #pragma unroll
    for (int nf = 0; nf < 4; ++nf) {
      int n = n0 + wc * 64 + nf * 16 + li;
      if (n < Nlim) {
        #pragma unroll
        for (int mf = 0; mf < 8; ++mf) {
          int m = m0 + wrM * 128 + mf * 16 + kq * 4;
          #pragma unroll
          for (int rr = 0; rr < 4; ++rr)
            Cf[(u32)(m + rr) * (u32)ldc + n] = acc[mf][nf][rr];
        }
      }
    }
  }
}

// ---------- softmax + argmax (top-2 flag + candidate-pair emission) ----------
__global__ __launch_bounds__(256) void k_softmax(u32* __restrict__ score, float* __restrict__ offs,
                                                 int* __restrict__ rlist, int* __restrict__ rcount,
                                                 u32* __restrict__ pairs, int* __restrict__ pcount) {
  int q = blockIdx.x;
  u32* row = score + (size_t)q * L_;
  int tid = threadIdx.x;
  int wid = tid >> 6, lane = tid & 63;
  __shared__ float smax[4]; __shared__ int sidx[4]; __shared__ float smax2[4]; __shared__ float ssum[4];
  __shared__ int sflag;

  float v[16];
  float v1 = -3.4e38f, v2 = -3.4e38f; int i1 = 0;
  #pragma unroll
  for (int i = 0; i < 16; ++i) {
    int idx = tid + i * 256;
    u32 w = row[idx];
    v[i] = bf16f(w >> 16) + bf16f(w & 0xffffu);
    if (v[i] > v1 || (v[i] == v1 && idx < i1)) { v2 = v1; v1 = v[i]; i1 = idx; }
    else if (v[i] > v2) v2 = v[i];
  }
  #pragma unroll
  for (int off = 32; off; off >>= 1) {
    float ov1 = __shfl_down(v1, off);
    int   oi1 = __shfl_down(i1, off);
    float ov2 = __shfl_down(v2, off);
    if (ov1 > v1 || (ov1 == v1 && oi1 < i1)) { v2 = fmaxf(fmaxf(v2, ov2), v1); v1 = ov1; i1 = oi1; }
    else v2 = fmaxf(fmaxf(v2, ov2), ov1);
  }
  if (lane == 0) { smax[wid] = v1; sidx[wid] = i1; smax2[wid] = v2; }
  __syncthreads();
  if (tid == 0) {
    v1 = smax[0]; i1 = sidx[0]; v2 = smax2[0];
    for (int w = 1; w < 4; ++w) {
      if (smax[w] > v1 || (smax[w] == v1 && sidx[w] < i1)) {
        v2 = fmaxf(fmaxf(v2, smax2[w]), v1); v1 = smax[w]; i1 = sidx[w];
      } else v2 = fmaxf(fmaxf(v2, smax2[w]), smax[w]);
    }
    smax[0] = v1; sidx[0] = i1;
    sflag = (v1 - v2 <= TAU) ? 1 : 0;
    if (sflag) {
      int pos = atomicAdd(rcount, 1);
      if (pos < 4096) rlist[pos] = q;
    }
  }
  __syncthreads();
  float vmax = smax[0];

  if (sflag) {
    float thr = vmax - 2.0f * TAU;
    #pragma unroll
    for (int i = 0; i < 16; ++i) {
      if (v[i] >= thr) {
        int pos = atomicAdd(pcount, 1);
        if (pos < PAIRCAP) pairs[pos] = ((u32)q << 12) | (u32)(tid + i * 256);
      }
    }
  }

  float s = 0.f;
  #pragma unroll
  for (int i = 0; i < 16; ++i) { v[i] = expf((v[i] - vmax) * SCALE); s += v[i]; }
  #pragma unroll
  for (int off = 32; off; off >>= 1) s += __shfl_down(s, off);
  if (lane == 0) ssum[wid] = s;
  __syncthreads();
  if (tid == 0) ssum[0] = ssum[0] + ssum[1] + ssum[2] + ssum[3];
  __syncthreads();
  float inv = 1.f / ssum[0];
  #pragma unroll
  for (int i = 0; i < 16; ++i) {
    float a = v[i] * inv;
    u32 h = bf16rn(a);
    u32 lo = bf16rn(a - bf16f(h));
    row[tid + i * 256] = (h << 16) | lo;
  }
  if (tid == 0) offs[q] = (float)sidx[0];
}

// ---------- f64 rescue: one wave per (q,l) pair ----------
__global__ __launch_bounds__(256) void k_rpairs(const u32* __restrict__ pairs, const int* __restrict__ pcount,
                                                const float* __restrict__ b0, const float* __restrict__ m0,
                                                const float* __restrict__ fmb, const double* __restrict__ norme,
                                                u64* __restrict__ rbest) {
  int nw = gridDim.x * 4;
  int gw = blockIdx.x * 4 + (threadIdx.x >> 6);
  int lane = threadIdx.x & 63;
  int cnt = *pcount; if (cnt > PAIRCAP) cnt = PAIRCAP;
  for (int e = gw; e < cnt; e += nw) {
    u32 pr = pairs[e];
    int q = pr >> 12, l = pr & 4095;
    int qy = q >> 6, qx = q & 63, ly = l >> 6, lx = l & 63;
    int c = lane;
    double dot = 0.0;
    #pragma unroll
    for (int t = 0; t < 9; ++t) {
      int i = t / 3, j = t - (t / 3) * 3;
      int wy = ly + i - 1, wx = lx + j - 1;
      int fy = qy + i - 1, fx = qx + j - 1;
      float wv = 0.f, fv = 0.f;
      if ((unsigned)wy < 64u && (unsigned)wx < 64u) wv = b0[(c << 12) + (wy << 6) + wx] * m0[l * 9 + t];
      if ((unsigned)fy < 64u && (unsigned)fx < 64u) fv = fmb[(c << 12) + (fy << 6) + fx];
      dot += (double)wv * (double)fv;
    }
    #pragma unroll
    for (int off = 32; off; off >>= 1) dot += __shfl_down(dot, off);
    if (lane == 0) {
      double sc = dot / norme[l];
      u64 bbits = (u64)__double_as_longlong(sc);
      if (bbits >> 63) bbits = ~bbits; else bbits |= 0x8000000000000000ull;
      u64 key = (bbits & ~0xFFFull) | (u64)(4095 - l);
      atomicMax(rbest + q, key);
    }
  }
}

__global__ __launch_bounds__(256) void k_rfin(const int* __restrict__ rlist, const int* __restrict__ rcount,
                                              const u64* __restrict__ rbest, float* __restrict__ offs) {
  int cnt = *rcount; if (cnt > 4096) cnt = 4096;
  for (int e = blockIdx.x * 256 + threadIdx.x; e < cnt; e += gridDim.x * 256) {
    int q = rlist[e];
    offs[q] = (float)(4095 - (int)(rbest[q] & 0xFFFull));
  }
}

// ---------- fold: y[c,p] = sum over 9 taps x 4 K-parts ----------
__global__ __launch_bounds__(256) void k_fold(const float* __restrict__ Gp, float* __restrict__ yout) {
  int idx = blockIdx.x * 256 + threadIdx.x;   // c*4096 + p
  int c = idx >> 12, p = idx & 4095;
  int yy = p >> 6, xx = p & 63;
  float s = 0.f;
  #pragma unroll
  for (int t = 0; t < 9; ++t) {
    int i = t / 3, j = t - (t / 3) * 3;
    int qy = yy + 1 - i, qx = xx + 1 - j;
    if ((unsigned)qy < 64u && (unsigned)qx < 64u) {
      u32 base = (u32)((qy << 6) + qx) * D_ + c * 9 + t;
      #pragma unroll
      for (int z = 0; z < 4; ++z) s += Gp[(size_t)z * 2359296 + base];
    }
  }
  yout[idx] = s;
}

extern "C" void kernel_launch(void* const* d_in, const int* in_sizes, int n_in,
                              void* d_out, int out_size, void* d_ws, size_t ws_size,
                              hipStream_t stream) {
  const float* b_in = (const float*)d_in[0];
  const float* f_in = (const float*)d_in[1];
  const float* mask = (const float*)d_in[2];
  float* out = (float*)d_out;

  char* ws = (char*)d_ws;
  float* mp     = (float*)(ws + 0);
  float* m0buf  = (float*)(ws + 65536);
  float* fm     = (float*)(ws + 212992);
  float* normv  = (float*)(ws + 4407296);
  u16*   w_hi   = (u16*)(ws + 4423680);
  u16*   w_lo   = (u16*)(ws + 9142272);
  u16*   fp_hi  = (u16*)(ws + 13860864);
  u16*   fp_lo  = (u16*)(ws + 18579456);
  u16*   wT_hi  = (u16*)(ws + 23298048);
  u16*   wT_lo  = (u16*)(ws + 28540928);
  u32*   scoreP = (u32*)(ws + 33783808);
  float* Gpart  = (float*)(ws + 100892672);   // 4 x 4096 x 576 f32 -> ends 138641408
  int*   rcount = (int*)(ws + 138641408);
  int*   pcount = (int*)(ws + 138641412);
  int*   rlist  = (int*)(ws + 138641664);     // 4096 ints
  double* norme = (double*)(ws + 138657920);  // 4096 f64
  u64*   rbest  = (u64*)(ws + 138690688);     // 4096 u64
  u32*   pairs  = (u32*)(ws + 138723456);     // 262144 u32 -> ends 139771904

  k_mp<<<64, 256, 0, stream>>>(mask, mp);
  k_m0<<<144, 256, 0, stream>>>(mp, m0buf);
  k_fm<<<4096, 256, 0, stream>>>(f_in, mp, fm);

  for (int b = 0; b < B_; ++b) {
    const float* bimg = b_in + (size_t)b * C_ * HW;
    const float* fmb  = fm + (size_t)b * C_ * HW;
    float* offs_b = out + (size_t)B_ * C_ * HW + (size_t)b * HW;

    hipMemsetAsync(rcount, 0, 8, stream);                 // rcount + pcount
    hipMemsetAsync(rbest, 0, 4096 * sizeof(u64), stream);
    k_patch<<<9216, 256, 0, stream>>>(bimg, m0buf, w_hi, w_lo);
    k_norm<<<1024, 256, 0, stream>>>(w_hi, w_lo, normv);
    k_norme<<<1024, 256, 0, stream>>>(bimg, m0buf, norme);
    k_patchT<<<10240, 256, 0, stream>>>(bimg, m0buf, wT_hi, wT_lo);
    k_patch<<<9216, 256, 0, stream>>>(fmb, nullptr, fp_hi, fp_lo);
    // GEMM1: score[q,l] = fp.w / norm -> packed u32   (256x128 tiles: grid 32x16)
    k_mfma<false, true><<<dim3(32, 16, 1), 256, 0, stream>>>(
        fp_hi, fp_lo, w_hi, w_lo, normv, scoreP,
        D_, D_, L_, L_, 0, 18, 0);
    k_softmax<<<4096, 256, 0, stream>>>(scoreP, offs_b, rlist, rcount, pairs, pcount);
    // GEMM2: G[q,d] = attn.wT, split-K=4 partials     (256x128 tiles: grid 5x16x4)
    k_mfma<true, false><<<dim3(5, 16, 4), 256, 0, stream>>>(
        scoreP, nullptr, wT_hi, wT_lo, nullptr, Gpart,
        L_, L_, D_, D_, 1024, 32, 2359296);
    k_rpairs<<<512, 256, 0, stream>>>(pairs, pcount, bimg, m0buf, fmb, norme, rbest);
    k_rfin<<<16, 256, 0, stream>>>(rlist, rcount, rbest, offs_b);
    k_fold<<<1024, 256, 0, stream>>>(Gpart, out + (size_t)b * C_ * HW);
  }
}

// Round 6
// 823.621 us; speedup vs baseline: 6.5158x; 1.2298x over previous
//
#include <hip/hip_runtime.h>
#include <math.h>

typedef unsigned int u32;
typedef unsigned short u16;
typedef unsigned long long u64;
typedef short s8v __attribute__((ext_vector_type(8)));
typedef float f4v __attribute__((ext_vector_type(4)));

#define B_ 4
#define C_ 64
#define HW 4096
#define L_ 4096
#define D_ 576
#define MW 256
#define SCALE 10.0f
#define EPS 1e-4f
#define TAU 0.015f
#define PAIRCAP 262144

__device__ __forceinline__ u32 bf16rn(float x) {
  u32 u = __float_as_uint(x);
  return (u + 0x7fffu + ((u >> 16) & 1u)) >> 16;
}
__device__ __forceinline__ float bf16f(u32 h) { return __uint_as_float(h << 16); }

__device__ __forceinline__ void gld16(const void* g, void* l) {
  __builtin_amdgcn_global_load_lds((const __attribute__((address_space(1))) void*)g,
                                   (__attribute__((address_space(3))) void*)l, 16, 0, 0);
}

// ---------- small prep kernels ----------
__global__ __launch_bounds__(256) void k_mp(const float* __restrict__ mask, float* __restrict__ mp) {
  int idx = blockIdx.x * 256 + threadIdx.x;
  int b = idx >> 12, p = idx & 4095;
  int y = p >> 6, x = p & 63;
  const float* mb = mask + (size_t)b * MW * MW;
  float s = 0.f;
  #pragma unroll
  for (int i = 0; i < 4; ++i)
    #pragma unroll
    for (int j = 0; j < 4; ++j)
      s += mb[(y * 4 + i) * MW + x * 4 + j];
  mp[idx] = s * (1.f / 16.f);
}

__global__ __launch_bounds__(256) void k_m0(const float* __restrict__ mp, float* __restrict__ m0) {
  int idx = blockIdx.x * 256 + threadIdx.x;   // l*9 + t
  int l = idx / 9, t = idx - l * 9;
  int ly = l >> 6, lx = l & 63;
  int i = t / 3, j = t - i * 3;
  int yy = ly + i - 1, xx = lx + j - 1;
  float v = 0.f;
  if ((unsigned)yy < 64u && (unsigned)xx < 64u) v = mp[(yy << 6) + xx];
  m0[idx] = v;
}

__global__ __launch_bounds__(256) void k_fm(const float* __restrict__ f, const float* __restrict__ mp,
                                            float* __restrict__ fm) {
  int idx = blockIdx.x * 256 + threadIdx.x;
  int p = idx & 4095;
  int b = idx >> 18;
  fm[idx] = f[idx] * (1.f - mp[(b << 12) + p]);
}

// patches row-major [l][576] -> hi/lo bf16 planes (GEMM1 operands)
__global__ __launch_bounds__(256) void k_patch(const float* __restrict__ img,
                                               const float* __restrict__ m0,
                                               u16* __restrict__ oh, u16* __restrict__ ol) {
  int idx = blockIdx.x * 256 + threadIdx.x;   // l*576 + d
  int l = idx / D_;
  int d = idx - l * D_;
  int c = d / 9, t = d - c * 9;
  int ly = l >> 6, lx = l & 63;
  int i = t / 3, j = t - i * 3;
  int yy = ly + i - 1, xx = lx + j - 1;
  float v = 0.f;
  if ((unsigned)yy < 64u && (unsigned)xx < 64u) v = img[(c << 12) + (yy << 6) + xx];
  if (m0) v *= m0[l * 9 + t];
  u32 h = bf16rn(v);
  oh[idx] = (u16)h;
  ol[idx] = (u16)bf16rn(v - bf16f(h));
}

// transposed patches [d<640][4096 l] -> single bf16 plane (GEMM2 B)
__global__ __launch_bounds__(256) void k_patchT(const float* __restrict__ img,
                                                const float* __restrict__ m0,
                                                u16* __restrict__ oh) {
  int idx = blockIdx.x * 256 + threadIdx.x;   // d*4096 + l
  int d = idx >> 12, l = idx & 4095;
  float v = 0.f;
  if (d < D_) {
    int c = d / 9, t = d - c * 9;
    int ly = l >> 6, lx = l & 63;
    int i = t / 3, j = t - i * 3;
    int yy = ly + i - 1, xx = lx + j - 1;
    if ((unsigned)yy < 64u && (unsigned)xx < 64u)
      v = img[(c << 12) + (yy << 6) + xx] * m0[l * 9 + t];
  }
  oh[idx] = (u16)bf16rn(v);
}

// exact f64 norm per l; also emits f32 copy for the GEMM1 epilogue
__global__ __launch_bounds__(256) void k_norme(const float* __restrict__ b0, const float* __restrict__ m0,
                                               double* __restrict__ norme, float* __restrict__ normv) {
  int l = blockIdx.x * 4 + (threadIdx.x >> 6);
  int lane = threadIdx.x & 63;
  int ly = l >> 6, lx = l & 63;
  double s = 0.0;
  for (int i = lane; i < D_; i += 64) {
    int c = i / 9, t = i - c * 9;
    int ii = t / 3, jj = t - ii * 3;
    int yy = ly + ii - 1, xx = lx + jj - 1;
    if ((unsigned)yy < 64u && (unsigned)xx < 64u) {
      float wv = b0[(c << 12) + (yy << 6) + xx] * m0[l * 9 + t];
      s += (double)wv * (double)wv;
    }
  }
  #pragma unroll
  for (int off = 32; off; off >>= 1) s += __shfl_down(s, off);
  if (lane == 0) {
    double n = sqrt(s + (double)EPS);
    norme[l] = n;
    normv[l] = (float)n;
  }
}

// ---------- MFMA GEMM: block 256x128, 4 waves, per-wave 128x64 ----------
// MODE 0 (GEMM1): 3-term hi/lo split, epilogue /normv[n] -> f32 C, ldc=4096.
// MODE 1 (GEMM2): single bf16 term, split-K partials -> f32 C (+z*czStride), n<Nlim guard.
template<int MODE>
__global__ __launch_bounds__(256, 2) void k_mfma(
    const u16* __restrict__ Ah, const u16* __restrict__ Al,
    const u16* __restrict__ Bh, const u16* __restrict__ Bl,
    const float* __restrict__ normv, float* __restrict__ Cout,
    int lda, int ldb, int ldc, int Nlim, int kPerZ, int nChunks, int czStride)
{
  __shared__ u32 lds[(MODE == 0) ? 12288 : 6144];
  u16* ldsu = (u16*)lds;
  const int tid = threadIdx.x;
  const int lane = tid & 63, wid = tid >> 6;
  const int wrM = wid >> 1, wc = wid & 1;
  const int kq = lane >> 4, li = lane & 15;

  int nwg = gridDim.x * gridDim.y;
  int bid = blockIdx.y * gridDim.x + blockIdx.x;
  int cpx = nwg >> 3;                 // 512 and 80 both divisible by 8
  int swz = (bid & 7) * cpx + (bid >> 3);
  int bx = swz % gridDim.x, by = swz / gridDim.x;
  const int m0 = by * 256, n0 = bx * 128;
  const int kz = blockIdx.z * kPerZ;

  f4v acc[8][4] = {};

  for (int kc = 0; kc < nChunks; ++kc) {
    int k0 = kz + kc * 32;
    // A staging: 256 rows x 32 k x 2B per plane = 1024 slots of 16B
    #pragma unroll
    for (int i = 0; i < 4; ++i) {
      int s = tid + i * 256;
      int r = s >> 2, ks = s & 3;
      int kg = ks ^ ((r >> 1) & 3);
      u32 go = (u32)(m0 + r) * (u32)lda + (u32)(k0 + kg * 8);
      gld16(Ah + go, (char*)lds + s * 16);
      if (MODE == 0) gld16(Al + go, (char*)lds + 16384 + s * 16);
    }
    // B staging: 128 rows x 32 k x 2B per plane = 512 slots of 16B
    #pragma unroll
    for (int i = 0; i < 2; ++i) {
      int s = tid + i * 256;
      int r = s >> 2, ks = s & 3;
      int kg = ks ^ ((r >> 1) & 3);
      u32 go = (u32)(n0 + r) * (u32)ldb + (u32)(k0 + kg * 8);
      if (MODE == 0) {
        gld16(Bh + go, (char*)lds + 32768 + s * 16);
        gld16(Bl + go, (char*)lds + 40960 + s * 16);
      } else {
        gld16(Bh + go, (char*)lds + 16384 + s * 16);
      }
    }
    __syncthreads();

    s8v ah[8], alv[8];
    #pragma unroll
    for (int mf = 0; mf < 8; ++mf) {
      int r = wrM * 128 + mf * 16 + li;
      int off = r * 32 + (kq ^ ((r >> 1) & 3)) * 8;
      ah[mf] = *(const s8v*)&ldsu[off];
      if (MODE == 0) alv[mf] = *(const s8v*)&ldsu[8192 + off];
    }
    #pragma unroll
    for (int nf = 0; nf < 4; ++nf) {
      int r = wc * 64 + nf * 16 + li;
      int off = r * 32 + (kq ^ ((r >> 1) & 3)) * 8;
      if (MODE == 0) {
        s8v bh = *(const s8v*)&ldsu[16384 + off];
        s8v bl = *(const s8v*)&ldsu[20480 + off];
        #pragma unroll
        for (int mf = 0; mf < 8; ++mf) {
          acc[mf][nf] = __builtin_amdgcn_mfma_f32_16x16x32_bf16(ah[mf],  bh, acc[mf][nf], 0, 0, 0);
          acc[mf][nf] = __builtin_amdgcn_mfma_f32_16x16x32_bf16(ah[mf],  bl, acc[mf][nf], 0, 0, 0);
          acc[mf][nf] = __builtin_amdgcn_mfma_f32_16x16x32_bf16(alv[mf], bh, acc[mf][nf], 0, 0, 0);
        }
      } else {
        s8v bh = *(const s8v*)&ldsu[8192 + off];
        #pragma unroll
        for (int mf = 0; mf < 8; ++mf)
          acc[mf][nf] = __builtin_amdgcn_mfma_f32_16x16x32_bf16(ah[mf], bh, acc[mf][nf], 0, 0, 0);
      }
    }
    __syncthreads();
  }

  if (MODE == 0) {
    #pragma unroll
    for (int nf = 0; nf < 4; ++nf) {
      int n = n0 + wc * 64 + nf * 16 + li;
      float invn = 1.0f / normv[n];
      #pragma unroll
      for (int mf = 0; mf < 8; ++mf) {
        int m = m0 + wrM * 128 + mf * 16 + kq * 4;
        #pragma unroll
        for (int rr = 0; rr < 4; ++rr)
          Cout[(u32)(m + rr) * (u32)ldc + n] = acc[mf][nf][rr] * invn;
      }
    }
  } else {
    float* Cf = Cout + (size_t)blockIdx.z * czStride;
    #pragma unroll
    for (int nf = 0; nf < 4; ++nf) {
      int n = n0 + wc * 64 + nf * 16 + li;
      if (n < Nlim) {
        #pragma unroll
        for (int mf = 0; mf < 8; ++mf) {
          int m = m0 + wrM * 128 + mf * 16 + kq * 4;
          #pragma unroll
          for (int rr = 0; rr < 4; ++rr)
            Cf[(u32)(m + rr) * (u32)ldc + n] = acc[mf][nf][rr];
        }
      }
    }
  }
}

// ---------- softmax + argmax (f32 score in, bf16 attn out, rescue flagging) ----------
__global__ __launch_bounds__(256) void k_softmax(const float* __restrict__ score, u16* __restrict__ attn,
                                                 float* __restrict__ offs,
                                                 int* __restrict__ rlist, int* __restrict__ rcount,
                                                 u32* __restrict__ pairs, int* __restrict__ pcount) {
  int q = blockIdx.x;
  const float* row = score + (size_t)q * L_;
  u16* arow = attn + (size_t)q * L_;
  int tid = threadIdx.x;
  int wid = tid >> 6, lane = tid & 63;
  __shared__ float smax[4]; __shared__ int sidx[4]; __shared__ float smax2[4]; __shared__ float ssum[4];
  __shared__ int sflag;

  float v[16];
  float v1 = -3.4e38f, v2 = -3.4e38f; int i1 = 0;
  #pragma unroll
  for (int i = 0; i < 16; ++i) {
    int idx = tid + i * 256;
    v[i] = row[idx];
    if (v[i] > v1 || (v[i] == v1 && idx < i1)) { v2 = v1; v1 = v[i]; i1 = idx; }
    else if (v[i] > v2) v2 = v[i];
  }
  #pragma unroll
  for (int off = 32; off; off >>= 1) {
    float ov1 = __shfl_down(v1, off);
    int   oi1 = __shfl_down(i1, off);
    float ov2 = __shfl_down(v2, off);
    if (ov1 > v1 || (ov1 == v1 && oi1 < i1)) { v2 = fmaxf(fmaxf(v2, ov2), v1); v1 = ov1; i1 = oi1; }
    else v2 = fmaxf(fmaxf(v2, ov2), ov1);
  }
  if (lane == 0) { smax[wid] = v1; sidx[wid] = i1; smax2[wid] = v2; }
  __syncthreads();
  if (tid == 0) {
    v1 = smax[0]; i1 = sidx[0]; v2 = smax2[0];
    for (int w = 1; w < 4; ++w) {
      if (smax[w] > v1 || (smax[w] == v1 && sidx[w] < i1)) {
        v2 = fmaxf(fmaxf(v2, smax2[w]), v1); v1 = smax[w]; i1 = sidx[w];
      } else v2 = fmaxf(fmaxf(v2, smax2[w]), smax[w]);
    }
    smax[0] = v1; sidx[0] = i1;
    sflag = (v1 - v2 <= TAU) ? 1 : 0;
    if (sflag) {
      int pos = atomicAdd(rcount, 1);
      if (pos < 4096) rlist[pos] = q;
    }
  }
  __syncthreads();
  float vmax = smax[0];

  if (sflag) {
    float thr = vmax - 2.0f * TAU;
    #pragma unroll
    for (int i = 0; i < 16; ++i) {
      if (v[i] >= thr) {
        int pos = atomicAdd(pcount, 1);
        if (pos < PAIRCAP) pairs[pos] = ((u32)q << 12) | (u32)(tid + i * 256);
      }
    }
  }

  float s = 0.f;
  #pragma unroll
  for (int i = 0; i < 16; ++i) { v[i] = expf((v[i] - vmax) * SCALE); s += v[i]; }
  #pragma unroll
  for (int off = 32; off; off >>= 1) s += __shfl_down(s, off);
  if (lane == 0) ssum[wid] = s;
  __syncthreads();
  if (tid == 0) ssum[0] = ssum[0] + ssum[1] + ssum[2] + ssum[3];
  __syncthreads();
  float inv = 1.f / ssum[0];
  #pragma unroll
  for (int i = 0; i < 16; ++i)
    arow[tid + i * 256] = (u16)bf16rn(v[i] * inv);
  if (tid == 0) offs[q] = (float)sidx[0];
}

// ---------- f64 rescue: one wave per (q,l) pair ----------
__global__ __launch_bounds__(256) void k_rpairs(const u32* __restrict__ pairs, const int* __restrict__ pcount,
                                                const float* __restrict__ b0, const float* __restrict__ m0,
                                                const float* __restrict__ fmb, const double* __restrict__ norme,
                                                u64* __restrict__ rbest) {
  int nw = gridDim.x * 4;
  int gw = blockIdx.x * 4 + (threadIdx.x >> 6);
  int lane = threadIdx.x & 63;
  int cnt = *pcount; if (cnt > PAIRCAP) cnt = PAIRCAP;
  for (int e = gw; e < cnt; e += nw) {
    u32 pr = pairs[e];
    int q = pr >> 12, l = pr & 4095;
    int qy = q >> 6, qx = q & 63, ly = l >> 6, lx = l & 63;
    int c = lane;
    double dot = 0.0;
    #pragma unroll
    for (int t = 0; t < 9; ++t) {
      int i = t / 3, j = t - (t / 3) * 3;
      int wy = ly + i - 1, wx = lx + j - 1;
      int fy = qy + i - 1, fx = qx + j - 1;
      float wv = 0.f, fv = 0.f;
      if ((unsigned)wy < 64u && (unsigned)wx < 64u) wv = b0[(c << 12) + (wy << 6) + wx] * m0[l * 9 + t];
      if ((unsigned)fy < 64u && (unsigned)fx < 64u) fv = fmb[(c << 12) + (fy << 6) + fx];
      dot += (double)wv * (double)fv;
    }
    #pragma unroll
    for (int off = 32; off; off >>= 1) dot += __shfl_down(dot, off);
    if (lane == 0) {
      double sc = dot / norme[l];
      u64 bbits = (u64)__double_as_longlong(sc);
      if (bbits >> 63) bbits = ~bbits; else bbits |= 0x8000000000000000ull;
      u64 key = (bbits & ~0xFFFull) | (u64)(4095 - l);
      atomicMax(rbest + q, key);
    }
  }
}

__global__ __launch_bounds__(256) void k_rfin(const int* __restrict__ rlist, const int* __restrict__ rcount,
                                              const u64* __restrict__ rbest, float* __restrict__ offs) {
  int cnt = *rcount; if (cnt > 4096) cnt = 4096;
  for (int e = blockIdx.x * 256 + threadIdx.x; e < cnt; e += gridDim.x * 256) {
    int q = rlist[e];
    offs[q] = (float)(4095 - (int)(rbest[q] & 0xFFFull));
  }
}

// ---------- fold: y[c,p] = sum over 9 taps x 4 K-parts ----------
__global__ __launch_bounds__(256) void k_fold(const float* __restrict__ Gp, float* __restrict__ yout) {
  int idx = blockIdx.x * 256 + threadIdx.x;   // c*4096 + p
  int c = idx >> 12, p = idx & 4095;
  int yy = p >> 6, xx = p & 63;
  float s = 0.f;
  #pragma unroll
  for (int t = 0; t < 9; ++t) {
    int i = t / 3, j = t - (t / 3) * 3;
    int qy = yy + 1 - i, qx = xx + 1 - j;
    if ((unsigned)qy < 64u && (unsigned)qx < 64u) {
      u32 base = (u32)((qy << 6) + qx) * D_ + c * 9 + t;
      #pragma unroll
      for (int z = 0; z < 4; ++z) s += Gp[(size_t)z * 2359296 + base];
    }
  }
  yout[idx] = s;
}

extern "C" void kernel_launch(void* const* d_in, const int* in_sizes, int n_in,
                              void* d_out, int out_size, void* d_ws, size_t ws_size,
                              hipStream_t stream) {
  const float* b_in = (const float*)d_in[0];
  const float* f_in = (const float*)d_in[1];
  const float* mask = (const float*)d_in[2];
  float* out = (float*)d_out;

  char* ws = (char*)d_ws;
  float*  mp     = (float*)(ws + 0);          // 64KB
  float*  m0buf  = (float*)(ws + 65536);      // 144KB
  float*  fm     = (float*)(ws + 212992);     // 4MB
  float*  normv  = (float*)(ws + 4407296);    // 16KB
  double* norme  = (double*)(ws + 4423680);   // 32KB
  u16*    w_hi   = (u16*)(ws + 4456448);      // 4.7MB
  u16*    w_lo   = (u16*)(ws + 9175040);      // 4.7MB
  u16*    fp_hi  = (u16*)(ws + 13893632);     // 4.7MB
  u16*    fp_lo  = (u16*)(ws + 18612224);     // 4.7MB
  u16*    wT_hi  = (u16*)(ws + 23330816);     // 5.2MB (640x4096)
  u16*    attn   = (u16*)(ws + 28573696);     // 32MB
  float*  scoreF = (float*)(ws + 62128128);   // 64MB; Gpart aliases (score dead after softmax)
  float*  Gpart  = (float*)(ws + 62128128);   // 4 x 2359296 f32 = 37.7MB
  int*    rcount = (int*)(ws + 129236992);
  int*    pcount = (int*)(ws + 129236996);
  int*    rlist  = (int*)(ws + 129237248);    // 16KB
  u64*    rbest  = (u64*)(ws + 129253632);    // 32KB
  u32*    pairs  = (u32*)(ws + 129286400);    // 1MB -> ends 130334976

  k_mp<<<64, 256, 0, stream>>>(mask, mp);
  k_m0<<<144, 256, 0, stream>>>(mp, m0buf);
  k_fm<<<4096, 256, 0, stream>>>(f_in, mp, fm);

  for (int b = 0; b < B_; ++b) {
    const float* bimg = b_in + (size_t)b * C_ * HW;
    const float* fmb  = fm + (size_t)b * C_ * HW;
    float* offs_b = out + (size_t)B_ * C_ * HW + (size_t)b * HW;

    hipMemsetAsync(rcount, 0, 8, stream);                 // rcount + pcount
    hipMemsetAsync(rbest, 0, 4096 * sizeof(u64), stream);
    k_patch<<<9216, 256, 0, stream>>>(bimg, m0buf, w_hi, w_lo);
    k_norme<<<1024, 256, 0, stream>>>(bimg, m0buf, norme, normv);
    k_patchT<<<10240, 256, 0, stream>>>(bimg, m0buf, wT_hi);
    k_patch<<<9216, 256, 0, stream>>>(fmb, nullptr, fp_hi, fp_lo);
    // GEMM1: score[q,l] = fp.w / norm -> f32   (256x128 tiles: grid 32x16)
    k_mfma<0><<<dim3(32, 16, 1), 256, 0, stream>>>(
        fp_hi, fp_lo, w_hi, w_lo, normv, scoreF,
        D_, D_, L_, L_, 0, 18, 0);
    k_softmax<<<4096, 256, 0, stream>>>(scoreF, attn, offs_b, rlist, rcount, pairs, pcount);
    // GEMM2: G[q,d] = attn.wT, single bf16, split-K=4   (grid 5x16x4)
    k_mfma<1><<<dim3(5, 16, 4), 256, 0, stream>>>(
        attn, nullptr, wT_hi, nullptr, nullptr, Gpart,
        L_, L_, D_, D_, 1024, 32, 2359296);
    k_rpairs<<<512, 256, 0, stream>>>(pairs, pcount, bimg, m0buf, fmb, norme, rbest);
    k_rfin<<<16, 256, 0, stream>>>(rlist, rcount, rbest, offs_b);
    k_fold<<<1024, 256, 0, stream>>>(Gpart, out + (size_t)b * C_ * HW);
  }
}

// Round 7
// 653.205 us; speedup vs baseline: 8.2157x; 1.2609x over previous
//
#include <hip/hip_runtime.h>
#include <math.h>

typedef unsigned int u32;
typedef unsigned short u16;
typedef unsigned long long u64;
typedef _Float16 h8v __attribute__((ext_vector_type(8)));
typedef float f4v __attribute__((ext_vector_type(4)));

#define B_ 4
#define C_ 64
#define HW 4096
#define L_ 4096
#define D_ 576
#define MW 256
#define SCALE 10.0f
#define EPS 1e-4f
#define TAU 0.015f
#define PAIRCAP 262144

__device__ __forceinline__ u16 f16b(float x) {
  union { _Float16 h; u16 u; } c; c.h = (_Float16)x; return c.u;
}

__device__ __forceinline__ void gld16(const void* g, void* l) {
  __builtin_amdgcn_global_load_lds((const __attribute__((address_space(1))) void*)g,
                                   (__attribute__((address_space(3))) void*)l, 16, 0, 0);
}

// ---------- upfront kernels ----------
__global__ __launch_bounds__(256) void k_mp(const float* __restrict__ mask, float* __restrict__ mp) {
  int idx = blockIdx.x * 256 + threadIdx.x;
  int b = idx >> 12, p = idx & 4095;
  int y = p >> 6, x = p & 63;
  const float* mb = mask + (size_t)b * MW * MW;
  float s = 0.f;
  #pragma unroll
  for (int i = 0; i < 4; ++i)
    #pragma unroll
    for (int j = 0; j < 4; ++j)
      s += mb[(y * 4 + i) * MW + x * 4 + j];
  mp[idx] = s * (1.f / 16.f);
}

// m0 (144 blocks) + fm (4096 blocks)
__global__ __launch_bounds__(256) void k_pre2(const float* __restrict__ f, const float* __restrict__ mp,
                                              float* __restrict__ m0, float* __restrict__ fm) {
  int blk = blockIdx.x;
  if (blk < 144) {
    int idx = blk * 256 + threadIdx.x;   // l*9 + t
    int l = idx / 9, t = idx - l * 9;
    int ly = l >> 6, lx = l & 63;
    int i = t / 3, j = t - i * 3;
    int yy = ly + i - 1, xx = lx + j - 1;
    float v = 0.f;
    if ((unsigned)yy < 64u && (unsigned)xx < 64u) v = mp[(yy << 6) + xx];
    m0[idx] = v;
  } else {
    int idx = (blk - 144) * 256 + threadIdx.x;
    int p = idx & 4095;
    int b = idx >> 18;
    fm[idx] = f[idx] * (1.f - mp[(b << 12) + p]);
  }
}

// ---------- per-batch prep: patch-w | norme | patchT | patch-fp | zero ----------
__global__ __launch_bounds__(256) void k_prep(const float* __restrict__ bimg, const float* __restrict__ fmb,
                                              const float* __restrict__ m0,
                                              u16* __restrict__ w_h, u16* __restrict__ fp_h,
                                              u16* __restrict__ wT_h,
                                              double* __restrict__ norme, float* __restrict__ normv,
                                              int* __restrict__ rcount, int* __restrict__ pcount,
                                              u64* __restrict__ rbest) {
  int blk = blockIdx.x;
  if (blk < 9216) {                      // w patches [l][576] fp16
    int idx = blk * 256 + threadIdx.x;
    int l = idx / D_, d = idx - l * D_;
    int c = d / 9, t = d - c * 9;
    int ly = l >> 6, lx = l & 63;
    int i = t / 3, j = t - i * 3;
    int yy = ly + i - 1, xx = lx + j - 1;
    float v = 0.f;
    if ((unsigned)yy < 64u && (unsigned)xx < 64u)
      v = bimg[(c << 12) + (yy << 6) + xx] * m0[l * 9 + t];
    w_h[idx] = f16b(v);
  } else if (blk < 10240) {              // exact f64 norm + f32 copy
    int l = (blk - 9216) * 4 + (threadIdx.x >> 6);
    int lane = threadIdx.x & 63;
    int ly = l >> 6, lx = l & 63;
    double s = 0.0;
    for (int i = lane; i < D_; i += 64) {
      int c = i / 9, t = i - c * 9;
      int ii = t / 3, jj = t - ii * 3;
      int yy = ly + ii - 1, xx = lx + jj - 1;
      if ((unsigned)yy < 64u && (unsigned)xx < 64u) {
        float wv = bimg[(c << 12) + (yy << 6) + xx] * m0[l * 9 + t];
        s += (double)wv * (double)wv;
      }
    }
    #pragma unroll
    for (int off = 32; off; off >>= 1) s += __shfl_down(s, off);
    if (lane == 0) {
      double n = sqrt(s + (double)EPS);
      norme[l] = n; normv[l] = (float)n;
    }
  } else if (blk < 20480) {              // wT [d<640][4096] fp16
    int idx = (blk - 10240) * 256 + threadIdx.x;
    int d = idx >> 12, l = idx & 4095;
    float v = 0.f;
    if (d < D_) {
      int c = d / 9, t = d - c * 9;
      int ly = l >> 6, lx = l & 63;
      int i = t / 3, j = t - i * 3;
      int yy = ly + i - 1, xx = lx + j - 1;
      if ((unsigned)yy < 64u && (unsigned)xx < 64u)
        v = bimg[(c << 12) + (yy << 6) + xx] * m0[l * 9 + t];
    }
    wT_h[idx] = f16b(v);
  } else if (blk < 29696) {              // fp patches [q][576] fp16 (no mask)
    int idx = (blk - 20480) * 256 + threadIdx.x;
    int l = idx / D_, d = idx - l * D_;
    int c = d / 9, t = d - c * 9;
    int ly = l >> 6, lx = l & 63;
    int i = t / 3, j = t - i * 3;
    int yy = ly + i - 1, xx = lx + j - 1;
    float v = 0.f;
    if ((unsigned)yy < 64u && (unsigned)xx < 64u)
      v = fmb[(c << 12) + (yy << 6) + xx];
    fp_h[idx] = f16b(v);
  } else {                               // 16 blocks: zero rbest + counters
    int e = (blk - 29696) * 256 + threadIdx.x;
    rbest[e] = 0ull;
    if (e == 0) { *rcount = 0; *pcount = 0; }
  }
}

// ---------- fp16 MFMA GEMM: block 256x128, 4 waves, per-wave 128x64, 2-phase dbuf ----------
// DIVN=1 (GEMM1): epilogue * 1/normv[n] -> f32, full N.  DIVN=0 (GEMM2): split-K partials, n<Nlim.
#define STAGE(buf, k0) do {                                                              \
    int bb = (buf) * 24576;                                                              \
    _Pragma("unroll") for (int i_ = 0; i_ < 4; ++i_) {                                   \
      int s_ = tid + i_ * 256; int r_ = s_ >> 2, ks_ = s_ & 3;                           \
      int kg_ = ks_ ^ ((r_ >> 1) & 3);                                                   \
      gld16(A + (u32)(m0 + r_) * (u32)lda + (u32)((k0) + kg_ * 8),                       \
            (char*)lds + bb + s_ * 16); }                                                \
    _Pragma("unroll") for (int i_ = 0; i_ < 2; ++i_) {                                   \
      int s_ = tid + i_ * 256; int r_ = s_ >> 2, ks_ = s_ & 3;                           \
      int kg_ = ks_ ^ ((r_ >> 1) & 3);                                                   \
      gld16(Bm + (u32)(n0 + r_) * (u32)ldb + (u32)((k0) + kg_ * 8),                      \
            (char*)lds + bb + 16384 + s_ * 16); }                                        \
  } while (0)

template<int DIVN>
__global__ __launch_bounds__(256, 2) void k_mfma(
    const u16* __restrict__ A, const u16* __restrict__ Bm,
    const float* __restrict__ normv, float* __restrict__ Cout,
    int lda, int ldb, int ldc, int Nlim, int kPerZ, int nChunks, int czStride)
{
  __shared__ u32 lds[12288];             // 48KB = 2 x (A 16KB + B 8KB)
  u16* ldsu = (u16*)lds;
  const int tid = threadIdx.x;
  const int lane = tid & 63, wid = tid >> 6;
  const int wrM = wid >> 1, wc = wid & 1;
  const int kq = lane >> 4, li = lane & 15;

  int nwg = gridDim.x * gridDim.y;
  int bid = blockIdx.y * gridDim.x + blockIdx.x;
  int cpx = nwg >> 3;                    // 512 and 80 both divisible by 8
  int swz = (bid & 7) * cpx + (bid >> 3);
  int bx = swz % gridDim.x, by = swz / gridDim.x;
  const int m0 = by * 256, n0 = bx * 128;
  const int kz = blockIdx.z * kPerZ;

  f4v acc[8][4] = {};

  STAGE(0, kz);
  __syncthreads();

  for (int kc = 0; kc < nChunks; ++kc) {
    int cur = kc & 1;
    if (kc + 1 < nChunks) STAGE(cur ^ 1, kz + (kc + 1) * 32);

    int cb = cur * 12288;                // u16 units per buffer
    h8v ah[8];
    #pragma unroll
    for (int mf = 0; mf < 8; ++mf) {
      int r = wrM * 128 + mf * 16 + li;
      int off = r * 32 + (kq ^ ((r >> 1) & 3)) * 8;
      ah[mf] = *(const h8v*)&ldsu[cb + off];
    }
    #pragma unroll
    for (int nf = 0; nf < 4; ++nf) {
      int r = wc * 64 + nf * 16 + li;
      int off = r * 32 + (kq ^ ((r >> 1) & 3)) * 8;
      h8v bh = *(const h8v*)&ldsu[cb + 8192 + off];
      #pragma unroll
      for (int mf = 0; mf < 8; ++mf)
        acc[mf][nf] = __builtin_amdgcn_mfma_f32_16x16x32_f16(ah[mf], bh, acc[mf][nf], 0, 0, 0);
    }
    if (kc + 1 < nChunks) {
      asm volatile("s_waitcnt vmcnt(0)" ::: "memory");
      __builtin_amdgcn_s_barrier();
      __builtin_amdgcn_sched_barrier(0);
    }
  }

  if (DIVN) {
    #pragma unroll
    for (int nf = 0; nf < 4; ++nf) {
      int n = n0 + wc * 64 + nf * 16 + li;
      float invn = 1.0f / normv[n];
      #pragma unroll
      for (int mf = 0; mf < 8; ++mf) {
        int m = m0 + wrM * 128 + mf * 16 + kq * 4;
        #pragma unroll
        for (int rr = 0; rr < 4; ++rr)
          Cout[(u32)(m + rr) * (u32)ldc + n] = acc[mf][nf][rr] * invn;
      }
    }
  } else {
    float* Cf = Cout + (size_t)blockIdx.z * czStride;
    #pragma unroll
    for (int nf = 0; nf < 4; ++nf) {
      int n = n0 + wc * 64 + nf * 16 + li;
      if (n < Nlim) {
        #pragma unroll
        for (int mf = 0; mf < 8; ++mf) {
          int m = m0 + wrM * 128 + mf * 16 + kq * 4;
          #pragma unroll
          for (int rr = 0; rr < 4; ++rr)
            Cf[(u32)(m + rr) * (u32)ldc + n] = acc[mf][nf][rr];
        }
      }
    }
  }
}

// ---------- softmax + argmax (f32 score in, fp16 attn out, rescue flagging) ----------
__global__ __launch_bounds__(256) void k_softmax(const float* __restrict__ score, u16* __restrict__ attn,
                                                 float* __restrict__ offs,
                                                 int* __restrict__ rlist, int* __restrict__ rcount,
                                                 u32* __restrict__ pairs, int* __restrict__ pcount) {
  int q = blockIdx.x;
  const float* row = score + (size_t)q * L_;
  u16* arow = attn + (size_t)q * L_;
  int tid = threadIdx.x;
  int wid = tid >> 6, lane = tid & 63;
  __shared__ float smax[4]; __shared__ int sidx[4]; __shared__ float smax2[4]; __shared__ float ssum[4];
  __shared__ int sflag;

  float v[16];
  float v1 = -3.4e38f, v2 = -3.4e38f; int i1 = 0;
  #pragma unroll
  for (int i = 0; i < 16; ++i) {
    int idx = tid + i * 256;
    v[i] = row[idx];
    if (v[i] > v1 || (v[i] == v1 && idx < i1)) { v2 = v1; v1 = v[i]; i1 = idx; }
    else if (v[i] > v2) v2 = v[i];
  }
  #pragma unroll
  for (int off = 32; off; off >>= 1) {
    float ov1 = __shfl_down(v1, off);
    int   oi1 = __shfl_down(i1, off);
    float ov2 = __shfl_down(v2, off);
    if (ov1 > v1 || (ov1 == v1 && oi1 < i1)) { v2 = fmaxf(fmaxf(v2, ov2), v1); v1 = ov1; i1 = oi1; }
    else v2 = fmaxf(fmaxf(v2, ov2), ov1);
  }
  if (lane == 0) { smax[wid] = v1; sidx[wid] = i1; smax2[wid] = v2; }
  __syncthreads();
  if (tid == 0) {
    v1 = smax[0]; i1 = sidx[0]; v2 = smax2[0];
    for (int w = 1; w < 4; ++w) {
      if (smax[w] > v1 || (smax[w] == v1 && sidx[w] < i1)) {
        v2 = fmaxf(fmaxf(v2, smax2[w]), v1); v1 = smax[w]; i1 = sidx[w];
      } else v2 = fmaxf(fmaxf(v2, smax2[w]), smax[w]);
    }
    smax[0] = v1; sidx[0] = i1;
    sflag = (v1 - v2 <= TAU) ? 1 : 0;
    if (sflag) {
      int pos = atomicAdd(rcount, 1);
      if (pos < 4096) rlist[pos] = q;
    }
  }
  __syncthreads();
  float vmax = smax[0];

  if (sflag) {
    float thr = vmax - 2.0f * TAU;
    #pragma unroll
    for (int i = 0; i < 16; ++i) {
      if (v[i] >= thr) {
        int pos = atomicAdd(pcount, 1);
        if (pos < PAIRCAP) pairs[pos] = ((u32)q << 12) | (u32)(tid + i * 256);
      }
    }
  }

  float s = 0.f;
  #pragma unroll
  for (int i = 0; i < 16; ++i) { v[i] = expf((v[i] - vmax) * SCALE); s += v[i]; }
  #pragma unroll
  for (int off = 32; off; off >>= 1) s += __shfl_down(s, off);
  if (lane == 0) ssum[wid] = s;
  __syncthreads();
  if (tid == 0) ssum[0] = ssum[0] + ssum[1] + ssum[2] + ssum[3];
  __syncthreads();
  float inv = 1.f / ssum[0];
  #pragma unroll
  for (int i = 0; i < 16; ++i)
    arow[tid + i * 256] = f16b(v[i] * inv);
  if (tid == 0) offs[q] = (float)sidx[0];
}

// ---------- f64 rescue: one wave per (q,l) pair ----------
__global__ __launch_bounds__(256) void k_rpairs(const u32* __restrict__ pairs, const int* __restrict__ pcount,
                                                const float* __restrict__ b0, const float* __restrict__ m0,
                                                const float* __restrict__ fmb, const double* __restrict__ norme,
                                                u64* __restrict__ rbest) {
  int nw = gridDim.x * 4;
  int gw = blockIdx.x * 4 + (threadIdx.x >> 6);
  int lane = threadIdx.x & 63;
  int cnt = *pcount; if (cnt > PAIRCAP) cnt = PAIRCAP;
  for (int e = gw; e < cnt; e += nw) {
    u32 pr = pairs[e];
    int q = pr >> 12, l = pr & 4095;
    int qy = q >> 6, qx = q & 63, ly = l >> 6, lx = l & 63;
    int c = lane;
    double dot = 0.0;
    #pragma unroll
    for (int t = 0; t < 9; ++t) {
      int i = t / 3, j = t - (t / 3) * 3;
      int wy = ly + i - 1, wx = lx + j - 1;
      int fy = qy + i - 1, fx = qx + j - 1;
      float wv = 0.f, fv = 0.f;
      if ((unsigned)wy < 64u && (unsigned)wx < 64u) wv = b0[(c << 12) + (wy << 6) + wx] * m0[l * 9 + t];
      if ((unsigned)fy < 64u && (unsigned)fx < 64u) fv = fmb[(c << 12) + (fy << 6) + fx];
      dot += (double)wv * (double)fv;
    }
    #pragma unroll
    for (int off = 32; off; off >>= 1) dot += __shfl_down(dot, off);
    if (lane == 0) {
      double sc = dot / norme[l];
      u64 bbits = (u64)__double_as_longlong(sc);
      if (bbits >> 63) bbits = ~bbits; else bbits |= 0x8000000000000000ull;
      u64 key = (bbits & ~0xFFFull) | (u64)(4095 - l);
      atomicMax(rbest + q, key);
    }
  }
}

// ---------- fold (1024 blocks) + rescue finalize (16 blocks) ----------
__global__ __launch_bounds__(256) void k_foldfin(const float* __restrict__ Gp, float* __restrict__ yout,
                                                 const int* __restrict__ rlist, const int* __restrict__ rcount,
                                                 const u64* __restrict__ rbest, float* __restrict__ offs) {
  if (blockIdx.x < 1024) {
    int idx = blockIdx.x * 256 + threadIdx.x;   // c*4096 + p
    int c = idx >> 12, p = idx & 4095;
    int yy = p >> 6, xx = p & 63;
    float s = 0.f;
    #pragma unroll
    for (int t = 0; t < 9; ++t) {
      int i = t / 3, j = t - (t / 3) * 3;
      int qy = yy + 1 - i, qx = xx + 1 - j;
      if ((unsigned)qy < 64u && (unsigned)qx < 64u) {
        u32 base = (u32)((qy << 6) + qx) * D_ + c * 9 + t;
        #pragma unroll
        for (int z = 0; z < 4; ++z) s += Gp[(size_t)z * 2359296 + base];
      }
    }
    yout[idx] = s;
  } else {
    int cnt = *rcount; if (cnt > 4096) cnt = 4096;
    int e = (blockIdx.x - 1024) * 256 + threadIdx.x;
    if (e < cnt) {
      int q = rlist[e];
      offs[q] = (float)(4095 - (int)(rbest[q] & 0xFFFull));
    }
  }
}

extern "C" void kernel_launch(void* const* d_in, const int* in_sizes, int n_in,
                              void* d_out, int out_size, void* d_ws, size_t ws_size,
                              hipStream_t stream) {
  const float* b_in = (const float*)d_in[0];
  const float* f_in = (const float*)d_in[1];
  const float* mask = (const float*)d_in[2];
  float* out = (float*)d_out;

  char* ws = (char*)d_ws;
  float*  mp     = (float*)(ws + 0);          // 64KB
  float*  m0buf  = (float*)(ws + 65536);      // 144KB
  float*  fm     = (float*)(ws + 212992);     // 4MB
  float*  normv  = (float*)(ws + 4407296);    // 16KB
  double* norme  = (double*)(ws + 4423680);   // 32KB
  u16*    w_h    = (u16*)(ws + 4456448);      // 4.7MB
  u16*    fp_h   = (u16*)(ws + 9175040);      // 4.7MB
  u16*    wT_h   = (u16*)(ws + 13893632);     // 5.2MB (640x4096)
  u16*    attn   = (u16*)(ws + 19136512);     // 32MB fp16
  float*  scoreF = (float*)(ws + 52690944);   // 64MB; Gpart aliases (score dead after softmax)
  float*  Gpart  = (float*)(ws + 52690944);   // 4 x 2359296 f32 = 37.7MB
  int*    rcount = (int*)(ws + 119799808);
  int*    pcount = (int*)(ws + 119799812);
  int*    rlist  = (int*)(ws + 119800064);    // 16KB
  u64*    rbest  = (u64*)(ws + 119816448);    // 32KB
  u32*    pairs  = (u32*)(ws + 119849216);    // 1MB -> ends 120897792

  k_mp<<<64, 256, 0, stream>>>(mask, mp);
  k_pre2<<<4240, 256, 0, stream>>>(f_in, mp, m0buf, fm);

  for (int b = 0; b < B_; ++b) {
    const float* bimg = b_in + (size_t)b * C_ * HW;
    const float* fmb  = fm + (size_t)b * C_ * HW;
    float* offs_b = out + (size_t)B_ * C_ * HW + (size_t)b * HW;

    k_prep<<<29712, 256, 0, stream>>>(bimg, fmb, m0buf, w_h, fp_h, wT_h,
                                      norme, normv, rcount, pcount, rbest);
    // GEMM1: score[q,l] = fp.w / norm -> f32   (256x128 tiles: grid 32x16)
    k_mfma<1><<<dim3(32, 16, 1), 256, 0, stream>>>(
        fp_h, w_h, normv, scoreF, D_, D_, L_, L_, 0, 18, 0);
    k_softmax<<<4096, 256, 0, stream>>>(scoreF, attn, offs_b, rlist, rcount, pairs, pcount);
    // GEMM2: G[q,d] = attn.wT, split-K=4       (grid 5x16x4)
    k_mfma<0><<<dim3(5, 16, 4), 256, 0, stream>>>(
        attn, wT_h, nullptr, Gpart, L_, L_, D_, D_, 1024, 32, 2359296);
    k_rpairs<<<512, 256, 0, stream>>>(pairs, pcount, bimg, m0buf, fmb, norme, rbest);
    k_foldfin<<<1040, 256, 0, stream>>>(Gpart, out + (size_t)b * C_ * HW,
                                        rlist, rcount, rbest, offs_b);
  }
}